// Round 2
// baseline (867.542 us; speedup 1.0000x reference)
//
#include <hip/hip_runtime.h>
#include <hip/hip_bf16.h>
#include <math.h>

// ---------------------------------------------------------------------------
// CrossAttnMLP, barrier-free per-wave-strip design for gfx950.
//  k0: weight fp32->bf16 + zero BN stat slices
//  ka: x(fp32) -> pt=[pep|tcr] bf16   (streaming GEMM, no LDS, no barriers)
//  kb: pt -> h1_pre + BN1 stat slices (wave-private LDS, no barriers)
//  kc: BN1+gelu+h2 GEMM + BN2 stats   (wave-private, no barriers)
//  kd: BN2+gelu+final dot
// Every wave owns 16 rows end-to-end; MFMA 16x16x32 bf16 throughout.
// ---------------------------------------------------------------------------

typedef __attribute__((ext_vector_type(8))) __bf16 bf16x8;
typedef __attribute__((ext_vector_type(2))) __bf16 bf16x2;
typedef __attribute__((ext_vector_type(8))) short s16x8;
typedef __attribute__((ext_vector_type(4))) float f32x4;

union S8U { s16x8 s; bf16x8 b; int i[4]; };

#if defined(__has_builtin)
#if __has_builtin(__builtin_amdgcn_cvt_pk_bf16_f32)
#define HAVE_PK_BF16 1
#endif
#endif

__device__ __forceinline__ short f2b(float f) {
  union { float f; unsigned u; } v; v.f = f;
  unsigned r = v.u + 0x7fffu + ((v.u >> 16) & 1u);   // RNE
  return (short)(r >> 16);
}
__device__ __forceinline__ float b2f(short s) {
  union { unsigned u; float f; } v; v.u = ((unsigned)(unsigned short)s) << 16;
  return v.f;
}
__device__ __forceinline__ int cvt2(float lo, float hi) {
#ifdef HAVE_PK_BF16
  union { bf16x2 v; int i; } u;
  u.v = __builtin_amdgcn_cvt_pk_bf16_f32(lo, hi);
  return u.i;
#else
  return ((int)(unsigned short)f2b(lo)) | (((int)(unsigned short)f2b(hi)) << 16);
#endif
}
__device__ __forceinline__ s16x8 pack8(const float* a) {
  union { s16x8 s; int i[4]; } u;
  u.i[0] = cvt2(a[0], a[1]); u.i[1] = cvt2(a[2], a[3]);
  u.i[2] = cvt2(a[4], a[5]); u.i[3] = cvt2(a[6], a[7]);
  return u.s;
}
// tanh-form gelu, branch-free (max |err| vs erf-gelu ~3e-3)
__device__ __forceinline__ float gelu_f(float x) {
  float u = x * (0.7978845608028654f + 0.035677408136300125f * x * x);
  float e = __expf(2.0f * u);
  float t = 1.0f - 2.0f / (e + 1.0f);   // tanh(u); e=inf -> 1, e=0 -> -1
  return 0.5f * x * (1.0f + t);
}

__device__ __forceinline__ f32x4 mfma_bf16(const S8U& a, const S8U& b, f32x4 c) {
  return __builtin_amdgcn_mfma_f32_16x16x32_bf16(a.b, b.b, c, 0, 0, 0);
}

// GEMM: acc[n] += buf(16 x 128, row-major LDS, stride 136) @ W^T
// W row-major (out,k) global bf16; out col = wc0 + 16n + l16; k offset kw0.
template<int NKT, int NC>
__device__ __forceinline__ void gemm_w(const short* __restrict__ buf,
                                       const short* __restrict__ W, int ldw,
                                       int wc0, int kw0, int l16, int q,
                                       f32x4 (&acc)[NC]) {
#pragma unroll
  for (int kt = 0; kt < NKT; ++kt) {
    S8U a; a.s = *(const s16x8*)(buf + l16 * 136 + 32 * kt + 8 * q);
#pragma unroll
    for (int n = 0; n < NC; ++n) {
      S8U b;
      b.s = *(const s16x8*)(W + (size_t)(wc0 + 16 * n + l16) * ldw + kw0 + 32 * kt + 8 * q);
      acc[n] = mfma_bf16(a, b, acc[n]);
    }
  }
}

template<int NC>
__device__ __forceinline__ void zero_acc(f32x4 (&acc)[NC]) {
  f32x4 z = {0.f, 0.f, 0.f, 0.f};
#pragma unroll
  for (int n = 0; n < NC; ++n) acc[n] = z;
}

// C-layout (row = 4q+r, col = 16n+l16) -> row-major LDS buffer, +bias, opt gelu
__device__ __forceinline__ void store_c(const f32x4 (&acc)[8], const float* __restrict__ bias,
                                        short* dst, int l16, int q, bool do_gelu) {
#pragma unroll
  for (int n = 0; n < 8; ++n) {
    int col = 16 * n + l16;
    float bb = bias[col];
#pragma unroll
    for (int r = 0; r < 4; ++r) {
      float v = acc[n][r] + bb;
      if (do_gelu) v = gelu_f(v);
      dst[(4 * q + r) * 136 + col] = f2b(v);
    }
  }
}

// acc += bias + residual(buf); LayerNorm over 128 cols (in-register, 16-lane
// shuffles); result written back to buf (row-major bf16).
__device__ __forceinline__ void res_ln(f32x4 (&acc)[8], const float* __restrict__ bias,
                                       short* buf, const float* __restrict__ g,
                                       const float* __restrict__ bt, int l16, int q) {
  float gg[8], bb[8];
#pragma unroll
  for (int n = 0; n < 8; ++n) {
    int col = 16 * n + l16;
    float bv = bias[col];
    gg[n] = g[col]; bb[n] = bt[col];
#pragma unroll
    for (int r = 0; r < 4; ++r)
      acc[n][r] += bv + b2f(buf[(4 * q + r) * 136 + col]);
  }
#pragma unroll
  for (int r = 0; r < 4; ++r) {
    float s = 0.f, sq = 0.f;
#pragma unroll
    for (int n = 0; n < 8; ++n) { float v = acc[n][r]; s += v; sq += v * v; }
#pragma unroll
    for (int m = 1; m < 16; m <<= 1) { s += __shfl_xor(s, m); sq += __shfl_xor(sq, m); }
    float mu = s * (1.0f / 128.0f);
    float var = sq * (1.0f / 128.0f) - mu * mu;
    float rs = rsqrtf(var + 1e-5f);
#pragma unroll
    for (int n = 0; n < 8; ++n)
      buf[(4 * q + r) * 136 + 16 * n + l16] = f2b((acc[n][r] - mu) * rs * gg[n] + bb[n]);
  }
}

// FFN: act = LN(act + W2 @ gelu(W1 @ act + b1) + b2); S1 = 16x128 scratch.
__device__ __forceinline__ void ffn(short* act, short* S1,
                                    const short* __restrict__ w1, const float* __restrict__ b1,
                                    const short* __restrict__ w2, const float* __restrict__ b2,
                                    const float* __restrict__ g, const float* __restrict__ bt,
                                    int l16, int q) {
  f32x4 acc2[8];
  zero_acc(acc2);
#pragma unroll 1
  for (int c = 0; c < 4; ++c) {
    f32x4 h[8];
    zero_acc(h);
    gemm_w<4, 8>(act, w1, 128, 128 * c, 0, l16, q, h);
    store_c(h, b1 + 128 * c, S1, l16, q, true);
    gemm_w<4, 8>(S1, w2, 512, 0, 128 * c, l16, q, acc2);
  }
  res_ln(acc2, b2, act, g, bt, l16, q);
}

// ---------------------------------------------------------------------------
struct KaArgs {
  const float* x;
  const short *wpep, *wtcr;
  const float *bpep, *btcr;
  short* pt;
};

__global__ __launch_bounds__(64, 3) void ka_proj(KaArgs A) {
  const int lane = threadIdx.x;
  const int l16 = lane & 15, q = lane >> 4;
  const size_t R0 = (size_t)blockIdx.x * 16;
  const float* xp = A.x + (R0 + l16) * 864 + 8 * q;

  f32x4 acc[16];
  zero_acc(acc);

  float4 c0 = *(const float4*)(xp);
  float4 c1 = *(const float4*)(xp + 4);
#pragma unroll 1
  for (int t = 0; t < 27; ++t) {
    float4 n0 = c0, n1 = c1;
    if (t < 26) {
      n0 = *(const float4*)(xp + 32 * (t + 1));
      n1 = *(const float4*)(xp + 32 * (t + 1) + 4);
    }
    float av[8] = {c0.x, c0.y, c0.z, c0.w, c1.x, c1.y, c1.z, c1.w};
    S8U af; af.s = pack8(av);
    if (t < 12) {
      const short* W = A.wpep + l16 * 384 + 32 * t + 8 * q;
#pragma unroll
      for (int n = 0; n < 8; ++n) {
        S8U b; b.s = *(const s16x8*)(W + (size_t)n * 16 * 384);
        acc[n] = mfma_bf16(af, b, acc[n]);
      }
    } else {
      const short* W = A.wtcr + l16 * 480 + 32 * (t - 12) + 8 * q;
#pragma unroll
      for (int n = 0; n < 8; ++n) {
        S8U b; b.s = *(const s16x8*)(W + (size_t)n * 16 * 480);
        acc[8 + n] = mfma_bf16(af, b, acc[8 + n]);
      }
    }
    c0 = n0; c1 = n1;
  }
  short* ptp = A.pt + (R0 + 4 * q) * 256;
#pragma unroll
  for (int n = 0; n < 16; ++n) {
    int col = 16 * n + l16;
    float bb = (n < 8) ? A.bpep[col] : A.btcr[col - 128];
#pragma unroll
    for (int r = 0; r < 4; ++r)
      ptp[(size_t)r * 256 + col] = f2b(acc[n][r] + bb);
  }
}

// ---------------------------------------------------------------------------
struct KbArgs {
  const short* pt;
  const short *wvp, *wop, *wvt, *wot, *w1p, *w2p, *w1t, *w2t, *wh1;
  const float *bvp, *bop, *bvt, *bot;
  const float *g1p, *e1p, *g2p, *e2p, *g1t, *e1t, *g2t, *e2t;
  const float *b1p, *b2p, *b1t, *b2t, *bh1;
  float* stats;
  short* h1;
};

__global__ __launch_bounds__(64, 3) void kb_body(KbArgs A) {
  __shared__ __align__(16) short L[3 * 16 * 136];
  short* U = L;                 // pep -> pa
  short* V = L + 16 * 136;      // tcr -> ta
  short* S1 = L + 2 * 16 * 136; // scratch (T / H / ffn hidden chunk)
  const int lane = threadIdx.x;
  const int l16 = lane & 15, q = lane >> 4;
  const size_t R0 = (size_t)blockIdx.x * 16;

  // load pt -> U,V (16B chunks; q<2 -> U, q>=2 -> V)
  {
    const short* p = A.pt + (R0 + l16) * 256 + 64 * q;
#pragma unroll
    for (int jj = 0; jj < 8; ++jj) {
      s16x8 vv = *(const s16x8*)(p + 8 * jj);
      int c = 64 * q + 8 * jj;
      if (q < 2) *(s16x8*)(U + l16 * 136 + c) = vv;
      else       *(s16x8*)(V + l16 * 136 + c - 128) = vv;
    }
  }

  // attention value projections (results held in registers)
  f32x4 accT[8], accH[8];
  zero_acc(accT); zero_acc(accH);
  gemm_w<4, 8>(V, A.wvp, 128, 0, 0, l16, q, accT);  // T = tcr @ wv_p2t^T
  gemm_w<4, 8>(U, A.wvt, 128, 0, 0, l16, q, accH);  // H = pep @ wv_t2p^T

  f32x4 acc[8];
  // pa = LN(pep + T @ wo_p2t^T + bo)
  store_c(accT, A.bvp, S1, l16, q, false);
  zero_acc(acc);
  gemm_w<4, 8>(S1, A.wop, 128, 0, 0, l16, q, acc);
  res_ln(acc, A.bop, U, A.g1p, A.e1p, l16, q);
  // ta = LN(tcr + H @ wo_t2p^T + bo)
  store_c(accH, A.bvt, S1, l16, q, false);
  zero_acc(acc);
  gemm_w<4, 8>(S1, A.wot, 128, 0, 0, l16, q, acc);
  res_ln(acc, A.bot, V, A.g1t, A.e1t, l16, q);

  ffn(U, S1, A.w1p, A.b1p, A.w2p, A.b2p, A.g2p, A.e2p, l16, q);
  ffn(V, S1, A.w1t, A.b1t, A.w2t, A.b2t, A.g2t, A.e2t, l16, q);

  // h1_pre = [pa|ta] @ w_h1^T + b_h1 ; BN1 partial stats (sliced atomics)
  zero_acc(acc);
  gemm_w<4, 8>(U, A.wh1, 256, 0, 0, l16, q, acc);
  gemm_w<4, 8>(V, A.wh1, 256, 0, 128, l16, q, acc);
  const int slice = blockIdx.x & 15;
  short* hp = A.h1 + (R0 + 4 * q) * 128;
#pragma unroll
  for (int n = 0; n < 8; ++n) {
    int col = 16 * n + l16;
    float bb = A.bh1[col];
    float s = 0.f, sq = 0.f;
#pragma unroll
    for (int r = 0; r < 4; ++r) {
      float v = acc[n][r] + bb;
      s += v; sq += v * v;
      hp[(size_t)r * 128 + col] = f2b(v);
    }
    s += __shfl_xor(s, 16); sq += __shfl_xor(sq, 16);
    s += __shfl_xor(s, 32); sq += __shfl_xor(sq, 32);
    if (q == 0) {
      atomicAdd(&A.stats[slice * 128 + col], s);
      atomicAdd(&A.stats[2048 + slice * 128 + col], sq);
    }
  }
}

// ---------------------------------------------------------------------------
struct KcArgs {
  const short* h1;
  const short* wh2;
  const float *bh2, *bn1g, *bn1b;
  float* stats;
  short* h2;
};

__global__ __launch_bounds__(64, 4) void kc_bn1(KcArgs A) {
  __shared__ float s1[128], t1[128];
  const int lane = threadIdx.x;
  const int l16 = lane & 15, q = lane >> 4;
  const size_t R0 = (size_t)blockIdx.x * 16;

  // finalize BN1 coefficients (single wave: in-order DS, no barrier needed)
#pragma unroll
  for (int j = 0; j < 2; ++j) {
    int c = 2 * lane + j;
    float S = 0.f, Q = 0.f;
#pragma unroll
    for (int s = 0; s < 16; ++s) {
      S += A.stats[s * 128 + c];
      Q += A.stats[2048 + s * 128 + c];
    }
    float mu = S * (1.0f / 65536.0f);
    float var = Q * (1.0f / 65536.0f) - mu * mu;
    float sc = A.bn1g[c] * rsqrtf(var + 1e-5f);
    s1[c] = sc;
    t1[c] = A.bn1b[c] - mu * sc;
  }

  f32x4 acc[4];
  zero_acc(acc);
  const short* hp = A.h1 + (R0 + l16) * 128 + 8 * q;
#pragma unroll
  for (int kt = 0; kt < 4; ++kt) {
    S8U gv; gv.s = *(const s16x8*)(hp + 32 * kt);
    f32x4 sA = *(const f32x4*)(s1 + 32 * kt + 8 * q);
    f32x4 sB = *(const f32x4*)(s1 + 32 * kt + 8 * q + 4);
    f32x4 tA = *(const f32x4*)(t1 + 32 * kt + 8 * q);
    f32x4 tB = *(const f32x4*)(t1 + 32 * kt + 8 * q + 4);
    float av[8];
#pragma unroll
    for (int i = 0; i < 4; ++i) av[i] = gelu_f(b2f(gv.s[i]) * sA[i] + tA[i]);
#pragma unroll
    for (int i = 0; i < 4; ++i) av[4 + i] = gelu_f(b2f(gv.s[4 + i]) * sB[i] + tB[i]);
    S8U f; f.s = pack8(av);
    const short* W = A.wh2 + l16 * 128 + 32 * kt + 8 * q;
#pragma unroll
    for (int n = 0; n < 4; ++n) {
      S8U b; b.s = *(const s16x8*)(W + (size_t)n * 16 * 128);
      acc[n] = mfma_bf16(f, b, acc[n]);
    }
  }
  const int slice = blockIdx.x & 15;
  short* op = A.h2 + (R0 + 4 * q) * 64;
#pragma unroll
  for (int n = 0; n < 4; ++n) {
    int col = 16 * n + l16;
    float bb = A.bh2[col];
    float s = 0.f, sq = 0.f;
#pragma unroll
    for (int r = 0; r < 4; ++r) {
      float v = acc[n][r] + bb;
      s += v; sq += v * v;
      op[(size_t)r * 64 + col] = f2b(v);
    }
    s += __shfl_xor(s, 16); sq += __shfl_xor(sq, 16);
    s += __shfl_xor(s, 32); sq += __shfl_xor(sq, 32);
    if (q == 0) {
      atomicAdd(&A.stats[4096 + slice * 64 + col], s);
      atomicAdd(&A.stats[5120 + slice * 64 + col], sq);
    }
  }
}

// ---------------------------------------------------------------------------
struct KdArgs {
  const short* h2;
  const float *bn2g, *bn2b;
  const float* stats;
  const float *wout, *bout;
  float* out;
};

__global__ __launch_bounds__(256) void kd_out(KdArgs A) {
  __shared__ float s2[64], t2[64], wo[64];
  const int tid = threadIdx.x;
  if (tid < 64) {
    float S = 0.f, Q = 0.f;
#pragma unroll
    for (int s = 0; s < 16; ++s) {
      S += A.stats[4096 + s * 64 + tid];
      Q += A.stats[5120 + s * 64 + tid];
    }
    float mu = S * (1.0f / 65536.0f);
    float var = Q * (1.0f / 65536.0f) - mu * mu;
    float sc = A.bn2g[tid] * rsqrtf(var + 1e-5f);
    s2[tid] = sc;
    t2[tid] = A.bn2b[tid] - mu * sc;
    wo[tid] = A.wout[tid];
  }
  __syncthreads();
  size_t row = (size_t)blockIdx.x * 32 + (tid >> 3);
  int c0 = (tid & 7) * 8;
  s16x8 hv = *(const s16x8*)(A.h2 + row * 64 + c0);
  float s = 0.f;
#pragma unroll
  for (int i = 0; i < 8; ++i) {
    float f = gelu_f(b2f(hv[i]) * s2[c0 + i] + t2[c0 + i]);
    s += f * wo[c0 + i];
  }
  s += __shfl_xor(s, 1); s += __shfl_xor(s, 2); s += __shfl_xor(s, 4);
  if ((tid & 7) == 0) A.out[row] = s + A.bout[0];
}

// ---------------------------------------------------------------------------
struct CvtArgs {
  const float* src[12];
  short* dst;
  float* stats;
};

// Each block converts 1024 elements; all segment boundaries are multiples of
// 1024. Blocks 0..23 also zero the 6144-float BN stat slices.
__global__ __launch_bounds__(256) void k0_setup(CvtArgs A) {
  const int cum[13] = {0, 49152, 110592, 126976, 143360, 159744, 176128,
                       241664, 307200, 372736, 438272, 471040, 479232};
  int b = blockIdx.x;
  if (b < 24) A.stats[b * 256 + threadIdx.x] = 0.0f;
  int base = b * 1024;
  int seg = 0;
#pragma unroll
  for (int t = 1; t < 12; ++t) seg += (base >= cum[t]) ? 1 : 0;
  const float* s = A.src[seg];
  int loc = base - cum[seg] + threadIdx.x * 4;
  float4 f = *(const float4*)(s + loc);
  int di = base + threadIdx.x * 4;
  int2 p;
  p.x = cvt2(f.x, f.y);
  p.y = cvt2(f.z, f.w);
  *(int2*)(A.dst + di) = p;
}

// ---------------------------------------------------------------------------
extern "C" void kernel_launch(void* const* d_in, const int* in_sizes, int n_in,
                              void* d_out, int out_size, void* d_ws, size_t ws_size,
                              hipStream_t stream) {
  (void)in_sizes; (void)n_in; (void)out_size; (void)ws_size;
  char* ws = (char*)d_ws;
  short* wb = (short*)ws;
  enum { O_PEP = 0, O_TCR = 49152, O_VP2T = 110592, O_OP2T = 126976,
         O_VT2P = 143360, O_OT2P = 159744, O_W1P = 176128, O_W2P = 241664,
         O_W1T = 307200, O_W2T = 372736, O_H1 = 438272, O_H2 = 471040 };
  float* stats  = (float*)(ws + 958464);    // 6144 floats (sliced BN stats)
  short* pt     = (short*)(ws + 983040);    // 65536 x 256 bf16
  short* h1_pre = (short*)(ws + 34537472);  // 65536 x 128 bf16
  short* h2_pre = (short*)(ws + 983040);    // overlays pt (dead after kb)

  CvtArgs ca;
  ca.src[0]  = (const float*)d_in[1];   // w_pep
  ca.src[1]  = (const float*)d_in[3];   // w_tcr
  ca.src[2]  = (const float*)d_in[5];   // wv_p2t
  ca.src[3]  = (const float*)d_in[7];   // wo_p2t
  ca.src[4]  = (const float*)d_in[9];   // wv_t2p
  ca.src[5]  = (const float*)d_in[11];  // wo_t2p
  ca.src[6]  = (const float*)d_in[21];  // ffn_w1p
  ca.src[7]  = (const float*)d_in[23];  // ffn_w2p
  ca.src[8]  = (const float*)d_in[25];  // ffn_w1t
  ca.src[9]  = (const float*)d_in[27];  // ffn_w2t
  ca.src[10] = (const float*)d_in[29];  // w_h1
  ca.src[11] = (const float*)d_in[33];  // w_h2
  ca.dst = wb;
  ca.stats = stats;
  k0_setup<<<468, 256, 0, stream>>>(ca);

  KaArgs a;
  a.x = (const float*)d_in[0];
  a.wpep = wb + O_PEP; a.wtcr = wb + O_TCR;
  a.bpep = (const float*)d_in[2];
  a.btcr = (const float*)d_in[4];
  a.pt = pt;
  ka_proj<<<4096, 64, 0, stream>>>(a);

  KbArgs b;
  b.pt = pt;
  b.wvp = wb + O_VP2T; b.wop = wb + O_OP2T;
  b.wvt = wb + O_VT2P; b.wot = wb + O_OT2P;
  b.w1p = wb + O_W1P;  b.w2p = wb + O_W2P;
  b.w1t = wb + O_W1T;  b.w2t = wb + O_W2T;
  b.wh1 = wb + O_H1;
  b.bvp = (const float*)d_in[6];
  b.bop = (const float*)d_in[8];
  b.bvt = (const float*)d_in[10];
  b.bot = (const float*)d_in[12];
  b.g1p = (const float*)d_in[13]; b.e1p = (const float*)d_in[14];
  b.g2p = (const float*)d_in[15]; b.e2p = (const float*)d_in[16];
  b.g1t = (const float*)d_in[17]; b.e1t = (const float*)d_in[18];
  b.g2t = (const float*)d_in[19]; b.e2t = (const float*)d_in[20];
  b.b1p = (const float*)d_in[22];
  b.b2p = (const float*)d_in[24];
  b.b1t = (const float*)d_in[26];
  b.b2t = (const float*)d_in[28];
  b.bh1 = (const float*)d_in[30];
  b.stats = stats;
  b.h1 = h1_pre;
  kb_body<<<4096, 64, 0, stream>>>(b);

  KcArgs c;
  c.h1 = h1_pre;
  c.wh2 = wb + O_H2;
  c.bh2 = (const float*)d_in[34];
  c.bn1g = (const float*)d_in[31];
  c.bn1b = (const float*)d_in[32];
  c.stats = stats;
  c.h2 = h2_pre;
  kc_bn1<<<4096, 64, 0, stream>>>(c);

  KdArgs d;
  d.h2 = h2_pre;
  d.bn2g = (const float*)d_in[35];
  d.bn2b = (const float*)d_in[36];
  d.stats = stats;
  d.wout = (const float*)d_in[37];
  d.bout = (const float*)d_in[38];
  d.out = (float*)d_out;
  kd_out<<<2048, 256, 0, stream>>>(d);
}

// Round 3
// 859.528 us; speedup vs baseline: 1.0093x; 1.0093x over previous
//
#include <hip/hip_runtime.h>
#include <hip/hip_bf16.h>
#include <math.h>

// ---------------------------------------------------------------------------
// CrossAttnMLP for gfx950 — 32-rows-per-wave, barrier-free body.
//  k0: weight fp32->bf16 + zero BN stat slices
//  kA: x -> [pep|tcr] -> attention -> FFNs -> h1 frags + BN1 sliced stats
//  kB: BN1+gelu -> h2 GEMM -> h2 frags + BN2 sliced stats
//  kC: BN2+gelu -> final dot -> out
// Each wave owns a 32-row strip (2 MFMA m-tiles); B-fragments amortized 2x.
// ---------------------------------------------------------------------------

typedef __attribute__((ext_vector_type(8))) __bf16 bf16x8;
typedef __attribute__((ext_vector_type(2))) __bf16 bf16x2;
typedef __attribute__((ext_vector_type(8))) short s16x8;
typedef __attribute__((ext_vector_type(4))) float f32x4;

union S8U { s16x8 s; bf16x8 b; int i[4]; };

#if defined(__has_builtin)
#if __has_builtin(__builtin_amdgcn_cvt_pk_bf16_f32)
#define HAVE_PK_BF16 1
#endif
#endif

__device__ __forceinline__ short f2b(float f) {
  union { float f; unsigned u; } v; v.f = f;
  unsigned r = v.u + 0x7fffu + ((v.u >> 16) & 1u);   // RNE
  return (short)(r >> 16);
}
__device__ __forceinline__ float b2f(short s) {
  union { unsigned u; float f; } v; v.u = ((unsigned)(unsigned short)s) << 16;
  return v.f;
}
__device__ __forceinline__ int cvt2(float lo, float hi) {
#ifdef HAVE_PK_BF16
  union { bf16x2 v; int i; } u;
  u.v = __builtin_amdgcn_cvt_pk_bf16_f32(lo, hi);
  return u.i;
#else
  return ((int)(unsigned short)f2b(lo)) | (((int)(unsigned short)f2b(hi)) << 16);
#endif
}
__device__ __forceinline__ s16x8 pack8(const float* a) {
  union { s16x8 s; int i[4]; } u;
  u.i[0] = cvt2(a[0], a[1]); u.i[1] = cvt2(a[2], a[3]);
  u.i[2] = cvt2(a[4], a[5]); u.i[3] = cvt2(a[6], a[7]);
  return u.s;
}
// tanh-form gelu, branch-free
__device__ __forceinline__ float gelu_f(float x) {
  float u = x * (0.7978845608028654f + 0.035677408136300125f * x * x);
  float e = __expf(2.0f * u);
  float t = 1.0f - 2.0f / (e + 1.0f);
  return 0.5f * x * (1.0f + t);
}

__device__ __forceinline__ f32x4 mfma_bf16(const S8U& a, const S8U& b, f32x4 c) {
  return __builtin_amdgcn_mfma_f32_16x16x32_bf16(a.b, b.b, c, 0, 0, 0);
}

template<int M, int NC>
__device__ __forceinline__ void zero_acc(f32x4 (&acc)[M][NC]) {
  f32x4 z = {0.f, 0.f, 0.f, 0.f};
#pragma unroll
  for (int m = 0; m < M; ++m)
#pragma unroll
    for (int n = 0; n < NC; ++n) acc[m][n] = z;
}

// acc[mt][n] += act(32x128 LDS, stride 136) @ W^T  (2 m-tiles share B-frags).
// W row-major (out,k); out col = wc0+16n+l16, k offset kw0+32kt+8q.
// Uniform base + single divergent offset -> SGPR-friendly addressing.
template<int NC>
__device__ __forceinline__ void gemm2(const short* __restrict__ act,
                                      const short* __restrict__ W, int ldw,
                                      int wc0, int kw0, int l16, int q,
                                      f32x4 (&acc)[2][NC]) {
  const short* Wp = W + (size_t)(wc0 + l16) * ldw + kw0 + 8 * q;
  const short* ap = act + l16 * 136 + 8 * q;
#pragma unroll
  for (int kt = 0; kt < 4; ++kt) {
    S8U a0, a1;
    a0.s = *(const s16x8*)(ap + 32 * kt);
    a1.s = *(const s16x8*)(ap + 16 * 136 + 32 * kt);
#pragma unroll
    for (int n = 0; n < NC; ++n) {
      S8U b;
      b.s = *(const s16x8*)(Wp + (size_t)n * 16 * ldw + 32 * kt);
      acc[0][n] = mfma_bf16(a0, b, acc[0][n]);
      acc[1][n] = mfma_bf16(a1, b, acc[1][n]);
    }
  }
}

// C-layout (rows 16mt+4q+r, col 16n+l16) -> row-major LDS, +bias, opt gelu.
__device__ __forceinline__ void store_c2(const f32x4 (&acc)[2][8], const float* __restrict__ bias,
                                         short* dst, int l16, int q, bool do_gelu) {
#pragma unroll
  for (int n = 0; n < 8; ++n) {
    int col = 16 * n + l16;
    float bb = bias[col];
#pragma unroll
    for (int mt = 0; mt < 2; ++mt)
#pragma unroll
      for (int r = 0; r < 4; ++r) {
        float v = acc[mt][n][r] + bb;
        if (do_gelu) v = gelu_f(v);
        dst[(16 * mt + 4 * q + r) * 136 + col] = f2b(v);
      }
  }
}

// acc += bias + residual(buf); per-16-row LayerNorm; write back to buf.
__device__ __forceinline__ void res_ln2(f32x4 (&acc)[2][8], const float* __restrict__ bias,
                                        short* buf, const float* __restrict__ g,
                                        const float* __restrict__ bt, int l16, int q) {
  float gg[8], bb[8];
#pragma unroll
  for (int n = 0; n < 8; ++n) {
    int col = 16 * n + l16;
    float bv = bias[col];
    gg[n] = g[col]; bb[n] = bt[col];
#pragma unroll
    for (int mt = 0; mt < 2; ++mt)
#pragma unroll
      for (int r = 0; r < 4; ++r)
        acc[mt][n][r] += bv + b2f(buf[(16 * mt + 4 * q + r) * 136 + col]);
  }
#pragma unroll
  for (int mt = 0; mt < 2; ++mt) {
#pragma unroll
    for (int r = 0; r < 4; ++r) {
      float s = 0.f, sq = 0.f;
#pragma unroll
      for (int n = 0; n < 8; ++n) { float v = acc[mt][n][r]; s += v; sq += v * v; }
#pragma unroll
      for (int m = 1; m < 16; m <<= 1) { s += __shfl_xor(s, m); sq += __shfl_xor(sq, m); }
      float mu = s * (1.0f / 128.0f);
      float var = sq * (1.0f / 128.0f) - mu * mu;
      float rs = rsqrtf(var + 1e-5f);
#pragma unroll
      for (int n = 0; n < 8; ++n)
        buf[(16 * mt + 4 * q + r) * 136 + 16 * n + l16] =
            f2b((acc[mt][n][r] - mu) * rs * gg[n] + bb[n]);
    }
  }
}

// FFN: act = LN(act + W2 @ gelu(W1 @ act + b1) + b2), 128-col chunks via S1.
__device__ __forceinline__ void ffn2(short* act, short* S1,
                                     const short* __restrict__ w1, const float* __restrict__ b1,
                                     const short* __restrict__ w2, const float* __restrict__ b2,
                                     const float* __restrict__ g, const float* __restrict__ bt,
                                     int l16, int q) {
  f32x4 acc2[2][8];
  zero_acc(acc2);
#pragma unroll 1
  for (int c = 0; c < 4; ++c) {
    f32x4 h[2][8];
    zero_acc(h);
    gemm2<8>(act, w1, 128, 128 * c, 0, l16, q, h);
    store_c2(h, b1 + 128 * c, S1, l16, q, true);
    gemm2<8>(S1, w2, 512, 0, 128 * c, l16, q, acc2);
  }
  res_ln2(acc2, b2, act, g, bt, l16, q);
}

// ---------------------------------------------------------------------------
struct KAArgs {
  const float* x;
  const short *wpep, *wtcr, *wvp, *wop, *wvt, *wot, *w1p, *w2p, *w1t, *w2t, *wh1;
  const float *bpep, *btcr, *bvp, *bop, *bvt, *bot;
  const float *g1p, *e1p, *g2p, *e2p, *g1t, *e1t, *g2t, *e2t;
  const float *b1p, *b2p, *b1t, *b2t, *bh1;
  float* stats;
  short* h1f;
};

__global__ __launch_bounds__(128, 2) void kA(KAArgs A) {
  __shared__ __align__(16) short L[2 * 3 * 32 * 136];
  const int tid = threadIdx.x;
  const int wv = tid >> 6, lane = tid & 63, l16 = lane & 15, q = lane >> 4;
  short* U  = L + wv * (3 * 32 * 136);
  short* V  = U + 32 * 136;
  short* S1 = V + 32 * 136;
  const int strip = blockIdx.x * 2 + wv;
  const size_t R0 = (size_t)strip * 32;

  // ---- phase 1: x -> pep(U), tcr(V); A-frags direct from global fp32 ----
  f32x4 accP[2][8], accQ[2][8];
  zero_acc(accP); zero_acc(accQ);
  const float* xp = A.x + (R0 + l16) * 864 + 8 * q;

  float4 c[2][4];
  auto ldx = [&](float4* d, int t) {
    d[0] = *(const float4*)(xp + 32 * t);
    d[1] = *(const float4*)(xp + 32 * t + 4);
    d[2] = *(const float4*)(xp + 16 * 864 + 32 * t);
    d[3] = *(const float4*)(xp + 16 * 864 + 32 * t + 4);
  };
  auto mkfrag = [&](const float4* cc, S8U& a0, S8U& a1) {
    float v0[8] = {cc[0].x, cc[0].y, cc[0].z, cc[0].w, cc[1].x, cc[1].y, cc[1].z, cc[1].w};
    float v1[8] = {cc[2].x, cc[2].y, cc[2].z, cc[2].w, cc[3].x, cc[3].y, cc[3].z, cc[3].w};
    a0.s = pack8(v0); a1.s = pack8(v1);
  };

  ldx(c[0], 0); ldx(c[1], 1);
#pragma unroll 1
  for (int t = 0; t < 12; ++t) {
    S8U a0, a1;
    mkfrag(c[t & 1], a0, a1);
    ldx(c[t & 1], t + 2);                       // steps 2..13
    const short* W = A.wpep + l16 * 384 + 32 * t + 8 * q;
#pragma unroll
    for (int n = 0; n < 8; ++n) {
      S8U b; b.s = *(const s16x8*)(W + (size_t)n * 16 * 384);
      accP[0][n] = mfma_bf16(a0, b, accP[0][n]);
      accP[1][n] = mfma_bf16(a1, b, accP[1][n]);
    }
  }
#pragma unroll 1
  for (int t = 0; t < 15; ++t) {                // global steps 12..26
    S8U a0, a1;
    mkfrag(c[t & 1], a0, a1);                   // (12+t)&1 == t&1
    if (t < 13) ldx(c[t & 1], 14 + t);
    const short* W = A.wtcr + l16 * 480 + 32 * t + 8 * q;
#pragma unroll
    for (int n = 0; n < 8; ++n) {
      S8U b; b.s = *(const s16x8*)(W + (size_t)n * 16 * 480);
      accQ[0][n] = mfma_bf16(a0, b, accQ[0][n]);
      accQ[1][n] = mfma_bf16(a1, b, accQ[1][n]);
    }
  }
  store_c2(accP, A.bpep, U, l16, q, false);
  store_c2(accQ, A.btcr, V, l16, q, false);

  // ---- phase 2: attention-equivalent projections + LN ----
  f32x4 accT[2][8], tmp[2][8];
  zero_acc(accT);
  gemm2<8>(V, A.wvp, 128, 0, 0, l16, q, accT);   // T = tcr @ wv_p2t^T (held)
  zero_acc(tmp);
  gemm2<8>(U, A.wvt, 128, 0, 0, l16, q, tmp);    // H = pep @ wv_t2p^T
  store_c2(tmp, A.bvt, S1, l16, q, false);
  zero_acc(tmp);
  gemm2<8>(S1, A.wot, 128, 0, 0, l16, q, tmp);
  res_ln2(tmp, A.bot, V, A.g1t, A.e1t, l16, q);  // V = ta
  store_c2(accT, A.bvp, S1, l16, q, false);
  zero_acc(tmp);
  gemm2<8>(S1, A.wop, 128, 0, 0, l16, q, tmp);
  res_ln2(tmp, A.bop, U, A.g1p, A.e1p, l16, q);  // U = pa

  // ---- phase 3: FFNs ----
  ffn2(U, S1, A.w1p, A.b1p, A.w2p, A.b2p, A.g2p, A.e2p, l16, q);
  ffn2(V, S1, A.w1t, A.b1t, A.w2t, A.b2t, A.g2t, A.e2t, l16, q);

  // ---- phase 4: h1 = [pa|ta] @ w_h1^T + b ; frag store + BN1 stats ----
  zero_acc(tmp);
  gemm2<8>(U, A.wh1, 256, 0, 0, l16, q, tmp);
  gemm2<8>(V, A.wh1, 256, 0, 128, l16, q, tmp);

  const int slice = strip & 15;
  short* hf = A.h1f + (size_t)strip * 4096 + lane * 64;
  union { short sh[64]; s16x8 v8[8]; } ob;
#pragma unroll
  for (int n = 0; n < 8; ++n) {
    int col = 16 * n + l16;
    float bb = A.bh1[col];
    float ss = 0.f, qq = 0.f;
#pragma unroll
    for (int mt = 0; mt < 2; ++mt)
#pragma unroll
      for (int r = 0; r < 4; ++r) {
        float v = tmp[mt][n][r] + bb;
        ss += v; qq += v * v;
        ob.sh[mt * 32 + n * 4 + r] = f2b(v);
      }
    ss += __shfl_xor(ss, 16); qq += __shfl_xor(qq, 16);
    ss += __shfl_xor(ss, 32); qq += __shfl_xor(qq, 32);
    if (q == 0) {
      atomicAdd(&A.stats[slice * 128 + col], ss);
      atomicAdd(&A.stats[2048 + slice * 128 + col], qq);
    }
  }
#pragma unroll
  for (int j = 0; j < 8; ++j) *(s16x8*)(hf + 8 * j) = ob.v8[j];
}

// ---------------------------------------------------------------------------
struct KBArgs {
  const short* h1f;
  const short* wh2;
  const float *bh2, *bn1g, *bn1b;
  float* stats;
  short* h2f;
};

__global__ __launch_bounds__(256, 4) void kB(KBArgs A) {
  __shared__ __align__(16) short SS[4 * 32 * 136];
  __shared__ float s1[128], t1[128];
  const int tid = threadIdx.x;
  const int wv = tid >> 6, lane = tid & 63, l16 = lane & 15, q = lane >> 4;
  const int strip = blockIdx.x * 4 + wv;

  if (tid < 128) {
    float S = 0.f, Q = 0.f;
#pragma unroll
    for (int s = 0; s < 16; ++s) {
      S += A.stats[s * 128 + tid];
      Q += A.stats[2048 + s * 128 + tid];
    }
    float mu = S * (1.0f / 65536.0f);
    float var = Q * (1.0f / 65536.0f) - mu * mu;
    float sc = A.bn1g[tid] * rsqrtf(var + 1e-5f);
    s1[tid] = sc;
    t1[tid] = A.bn1b[tid] - mu * sc;
  }
  __syncthreads();

  short* S1 = SS + wv * 32 * 136;
  const short* hf = A.h1f + (size_t)strip * 4096 + lane * 64;
  float sc[8], tc[8];
#pragma unroll
  for (int n = 0; n < 8; ++n) { int col = 16 * n + l16; sc[n] = s1[col]; tc[n] = t1[col]; }
#pragma unroll
  for (int j = 0; j < 8; ++j) {
    s16x8 v = *(const s16x8*)(hf + 8 * j);
    int mt = j >> 2;
#pragma unroll
    for (int e = 0; e < 8; ++e) {
      int n = (j & 3) * 2 + (e >> 2), r = e & 3;
      float f = gelu_f(b2f(v[e]) * sc[n] + tc[n]);
      S1[(16 * mt + 4 * q + r) * 136 + 16 * n + l16] = f2b(f);
    }
  }
  // wave-coherent LDS; no barrier needed (same pattern as verified r2 kb)
  f32x4 acc[2][4];
  zero_acc(acc);
  gemm2<4>(S1, A.wh2, 128, 0, 0, l16, q, acc);

  const int slice = strip & 15;
  short* of = A.h2f + (size_t)strip * 2048 + lane * 32;
  union { short sh[32]; s16x8 v8[4]; } ob;
#pragma unroll
  for (int n = 0; n < 4; ++n) {
    int col = 16 * n + l16;
    float bb = A.bh2[col];
    float ss = 0.f, qq = 0.f;
#pragma unroll
    for (int mt = 0; mt < 2; ++mt)
#pragma unroll
      for (int r = 0; r < 4; ++r) {
        float v = acc[mt][n][r] + bb;
        ss += v; qq += v * v;
        ob.sh[mt * 16 + n * 4 + r] = f2b(v);
      }
    ss += __shfl_xor(ss, 16); qq += __shfl_xor(qq, 16);
    ss += __shfl_xor(ss, 32); qq += __shfl_xor(qq, 32);
    if (q == 0) {
      atomicAdd(&A.stats[4096 + slice * 64 + col], ss);
      atomicAdd(&A.stats[5120 + slice * 64 + col], qq);
    }
  }
#pragma unroll
  for (int j = 0; j < 4; ++j) *(s16x8*)(of + 8 * j) = ob.v8[j];
}

// ---------------------------------------------------------------------------
struct KCArgs {
  const short* h2f;
  const float *bn2g, *bn2b;
  const float* stats;
  const float *wout, *bout;
  float* out;
};

__global__ __launch_bounds__(256, 4) void kC(KCArgs A) {
  __shared__ float cf[4][3][64];
  const int tid = threadIdx.x;
  const int wv = tid >> 6, lane = tid & 63, l16 = lane & 15, q = lane >> 4;
  const int strip = blockIdx.x * 4 + wv;
  const size_t R0 = (size_t)strip * 32;

  {
    float S = 0.f, Q = 0.f;
#pragma unroll
    for (int s = 0; s < 16; ++s) {
      S += A.stats[4096 + s * 64 + lane];
      Q += A.stats[5120 + s * 64 + lane];
    }
    float mu = S * (1.0f / 65536.0f);
    float var = Q * (1.0f / 65536.0f) - mu * mu;
    float sc = A.bn2g[lane] * rsqrtf(var + 1e-5f);
    cf[wv][0][lane] = sc;
    cf[wv][1][lane] = A.bn2b[lane] - mu * sc;
    cf[wv][2][lane] = A.wout[lane];
  }
  // wave-coherent LDS reads below (compiler waits lgkmcnt); no barrier
  const short* hf = A.h2f + (size_t)strip * 2048 + lane * 32;
  float rs[2][4] = {{0.f,0.f,0.f,0.f},{0.f,0.f,0.f,0.f}};
#pragma unroll
  for (int j = 0; j < 4; ++j) {
    s16x8 v = *(const s16x8*)(hf + 8 * j);
    int mt = j >> 1;
#pragma unroll
    for (int e = 0; e < 8; ++e) {
      int n = (j & 1) * 2 + (e >> 2), r = e & 3;
      int col = 16 * n + l16;
      float f = gelu_f(b2f(v[e]) * cf[wv][0][col] + cf[wv][1][col]) * cf[wv][2][col];
      rs[mt][r] += f;
    }
  }
#pragma unroll
  for (int mt = 0; mt < 2; ++mt)
#pragma unroll
    for (int r = 0; r < 4; ++r) {
#pragma unroll
      for (int m = 1; m < 16; m <<= 1) rs[mt][r] += __shfl_xor(rs[mt][r], m);
    }
  float bo = A.bout[0];
  if (l16 == 0) {
#pragma unroll
    for (int mt = 0; mt < 2; ++mt) {
      float4 o = {rs[mt][0] + bo, rs[mt][1] + bo, rs[mt][2] + bo, rs[mt][3] + bo};
      *(float4*)(A.out + R0 + 16 * mt + 4 * q) = o;
    }
  }
}

// ---------------------------------------------------------------------------
struct CvtArgs {
  const float* src[12];
  short* dst;
  float* stats;
};

__global__ __launch_bounds__(256) void k0_setup(CvtArgs A) {
  const int cum[13] = {0, 49152, 110592, 126976, 143360, 159744, 176128,
                       241664, 307200, 372736, 438272, 471040, 479232};
  int b = blockIdx.x;
  if (b < 24) A.stats[b * 256 + threadIdx.x] = 0.0f;
  int base = b * 1024;
  int seg = 0;
#pragma unroll
  for (int t = 1; t < 12; ++t) seg += (base >= cum[t]) ? 1 : 0;
  const float* s = A.src[seg];
  int loc = base - cum[seg] + threadIdx.x * 4;
  float4 f = *(const float4*)(s + loc);
  int di = base + threadIdx.x * 4;
  int2 p;
  p.x = cvt2(f.x, f.y);
  p.y = cvt2(f.z, f.w);
  *(int2*)(A.dst + di) = p;
}

// ---------------------------------------------------------------------------
extern "C" void kernel_launch(void* const* d_in, const int* in_sizes, int n_in,
                              void* d_out, int out_size, void* d_ws, size_t ws_size,
                              hipStream_t stream) {
  (void)in_sizes; (void)n_in; (void)out_size; (void)ws_size;
  char* ws = (char*)d_ws;
  short* wb = (short*)ws;
  enum { O_PEP = 0, O_TCR = 49152, O_VP2T = 110592, O_OP2T = 126976,
         O_VT2P = 143360, O_OT2P = 159744, O_W1P = 176128, O_W2P = 241664,
         O_W1T = 307200, O_W2T = 372736, O_H1 = 438272, O_H2 = 471040 };
  float* stats = (float*)(ws + 958464);     // 6144 floats
  short* h1f   = (short*)(ws + 983040);     // 2048 strips * 4096 shorts
  short* h2f   = (short*)(ws + 17760256);   // 2048 strips * 2048 shorts

  CvtArgs ca;
  ca.src[0]  = (const float*)d_in[1];   // w_pep
  ca.src[1]  = (const float*)d_in[3];   // w_tcr
  ca.src[2]  = (const float*)d_in[5];   // wv_p2t
  ca.src[3]  = (const float*)d_in[7];   // wo_p2t
  ca.src[4]  = (const float*)d_in[9];   // wv_t2p
  ca.src[5]  = (const float*)d_in[11];  // wo_t2p
  ca.src[6]  = (const float*)d_in[21];  // ffn_w1p
  ca.src[7]  = (const float*)d_in[23];  // ffn_w2p
  ca.src[8]  = (const float*)d_in[25];  // ffn_w1t
  ca.src[9]  = (const float*)d_in[27];  // ffn_w2t
  ca.src[10] = (const float*)d_in[29];  // w_h1
  ca.src[11] = (const float*)d_in[33];  // w_h2
  ca.dst = wb;
  ca.stats = stats;
  k0_setup<<<468, 256, 0, stream>>>(ca);

  KAArgs a;
  a.x = (const float*)d_in[0];
  a.wpep = wb + O_PEP; a.wtcr = wb + O_TCR;
  a.wvp = wb + O_VP2T; a.wop = wb + O_OP2T;
  a.wvt = wb + O_VT2P; a.wot = wb + O_OT2P;
  a.w1p = wb + O_W1P;  a.w2p = wb + O_W2P;
  a.w1t = wb + O_W1T;  a.w2t = wb + O_W2T;
  a.wh1 = wb + O_H1;
  a.bpep = (const float*)d_in[2];
  a.btcr = (const float*)d_in[4];
  a.bvp = (const float*)d_in[6];
  a.bop = (const float*)d_in[8];
  a.bvt = (const float*)d_in[10];
  a.bot = (const float*)d_in[12];
  a.g1p = (const float*)d_in[13]; a.e1p = (const float*)d_in[14];
  a.g2p = (const float*)d_in[15]; a.e2p = (const float*)d_in[16];
  a.g1t = (const float*)d_in[17]; a.e1t = (const float*)d_in[18];
  a.g2t = (const float*)d_in[19]; a.e2t = (const float*)d_in[20];
  a.b1p = (const float*)d_in[22];
  a.b2p = (const float*)d_in[24];
  a.b1t = (const float*)d_in[26];
  a.b2t = (const float*)d_in[28];
  a.bh1 = (const float*)d_in[30];
  a.stats = stats;
  a.h1f = h1f;
  kA<<<1024, 128, 0, stream>>>(a);

  KBArgs b;
  b.h1f = h1f;
  b.wh2 = wb + O_H2;
  b.bh2 = (const float*)d_in[34];
  b.bn1g = (const float*)d_in[31];
  b.bn1b = (const float*)d_in[32];
  b.stats = stats;
  b.h2f = h2f;
  kB<<<512, 256, 0, stream>>>(b);

  KCArgs c;
  c.h2f = h2f;
  c.bn2g = (const float*)d_in[35];
  c.bn2b = (const float*)d_in[36];
  c.stats = stats;
  c.wout = (const float*)d_in[37];
  c.bout = (const float*)d_in[38];
  c.out = (float*)d_out;
  kC<<<512, 256, 0, stream>>>(c);
}

// Round 4
// 838.987 us; speedup vs baseline: 1.0340x; 1.0245x over previous
//
#include <hip/hip_runtime.h>
#include <hip/hip_bf16.h>
#include <math.h>

// ---------------------------------------------------------------------------
// CrossAttnMLP for gfx950 — cooperative 64-row blocks (R1 structure) with:
//  - 3 LDS buffers (51 KB) -> 3 blocks/CU (12 waves/CU)
//  - phase-1 A-frags direct from global x (no staging LDS, no staging barriers)
//  - LN stats in the pad columns of the 136-stride buffers (no extra LDS)
//  - fragment-layout h1/h2 global buffers (coalesced b128 per lane)
//  k0: weights fp32->bf16 + zero BN stat slices
//  k1: x -> transformer body -> h1 frags + BN1 sliced stats
//  k2: BN1+gelu -> h2 GEMM -> h2 frags + BN2 sliced stats
//  k3: BN2+gelu -> final dot
// ---------------------------------------------------------------------------

typedef __attribute__((ext_vector_type(8))) __bf16 bf16x8;
typedef __attribute__((ext_vector_type(2))) __bf16 bf16x2;
typedef __attribute__((ext_vector_type(8))) short s16x8;
typedef __attribute__((ext_vector_type(4))) float f32x4;

union S8U { s16x8 s; bf16x8 b; int i[4]; };

#if defined(__has_builtin)
#if __has_builtin(__builtin_amdgcn_cvt_pk_bf16_f32)
#define HAVE_PK_BF16 1
#endif
#endif

__device__ __forceinline__ short f2b(float f) {
  union { float f; unsigned u; } v; v.f = f;
  unsigned r = v.u + 0x7fffu + ((v.u >> 16) & 1u);   // RNE
  return (short)(r >> 16);
}
__device__ __forceinline__ float b2f(short s) {
  union { unsigned u; float f; } v; v.u = ((unsigned)(unsigned short)s) << 16;
  return v.f;
}
__device__ __forceinline__ int cvt2(float lo, float hi) {
#ifdef HAVE_PK_BF16
  union { bf16x2 v; int i; } u;
  u.v = __builtin_amdgcn_cvt_pk_bf16_f32(lo, hi);
  return u.i;
#else
  return ((int)(unsigned short)f2b(lo)) | (((int)(unsigned short)f2b(hi)) << 16);
#endif
}
__device__ __forceinline__ s16x8 pack8(const float* a) {
  union { s16x8 s; int i[4]; } u;
  u.i[0] = cvt2(a[0], a[1]); u.i[1] = cvt2(a[2], a[3]);
  u.i[2] = cvt2(a[4], a[5]); u.i[3] = cvt2(a[6], a[7]);
  return u.s;
}
// tanh-form gelu, branch-free
__device__ __forceinline__ float gelu_f(float x) {
  float u = x * (0.7978845608028654f + 0.035677408136300125f * x * x);
  float e = __expf(2.0f * u);
  float t = 1.0f - 2.0f / (e + 1.0f);
  return 0.5f * x * (1.0f + t);
}

__device__ __forceinline__ f32x4 mfma_bf16(const S8U& a, const S8U& b, f32x4 c) {
  return __builtin_amdgcn_mfma_f32_16x16x32_bf16(a.b, b.b, c, 0, 0, 0);
}

template<int NC>
__device__ __forceinline__ void zero_acc4(f32x4 (&acc)[4][NC]) {
  f32x4 z = {0.f, 0.f, 0.f, 0.f};
#pragma unroll
  for (int mt = 0; mt < 4; ++mt)
#pragma unroll
    for (int n = 0; n < NC; ++n) acc[mt][n] = z;
}

// acc[mt][n] += act(64x128 LDS, stride 136) @ W^T.
// W row-major (out,k) bf16; out col = wc0 + 16n + l16, k = kw0 + 32kt + 8q..
template<int NC>
__device__ __forceinline__ void gemm4(const short* act,
                                      const short* __restrict__ W, int ldw,
                                      int wc0, int kw0, int l16, int q,
                                      f32x4 (&acc)[4][NC]) {
  const short* Wp = W + (size_t)(wc0 + l16) * ldw + kw0 + 8 * q;
  const short* ap = act + l16 * 136 + 8 * q;
#pragma unroll
  for (int kt = 0; kt < 4; ++kt) {
    S8U a[4];
#pragma unroll
    for (int mt = 0; mt < 4; ++mt)
      a[mt].s = *(const s16x8*)(ap + mt * 16 * 136 + 32 * kt);
#pragma unroll
    for (int n = 0; n < NC; ++n) {
      S8U b; b.s = *(const s16x8*)(Wp + (size_t)(16 * n) * ldw + 32 * kt);
#pragma unroll
      for (int mt = 0; mt < 4; ++mt) acc[mt][n] = mfma_bf16(a[mt], b, acc[mt][n]);
    }
  }
}

// C-layout (row=16mt+4q+r, col=32w+16n+l16) -> row-major LDS, +bias, opt gelu.
__device__ __forceinline__ void store_c4(const f32x4 (&acc)[4][2], const float* __restrict__ bias,
                                         short* dst, int w, int l16, int q, bool do_gelu) {
#pragma unroll
  for (int n = 0; n < 2; ++n) {
    int col = 32 * w + 16 * n + l16;
    float bb = bias[col];
#pragma unroll
    for (int mt = 0; mt < 4; ++mt)
#pragma unroll
      for (int r = 0; r < 4; ++r) {
        float v = acc[mt][n][r] + bb;
        if (do_gelu) v = gelu_f(v);
        dst[(16 * mt + 4 * q + r) * 136 + col] = f2b(v);
      }
  }
}

// acc += bias + residual(buf); LayerNorm over 128 cols; write back to buf.
// Cross-wave row stats flow through the pad columns (col 128..135) of U/V
// (partials, 2 floats per wave) and S1 (mu/rsigma) — no dedicated LDS.
__device__ __forceinline__ void res_ln4(f32x4 (&acc)[4][2], const float* __restrict__ bias,
                                        short* buf, const float* __restrict__ g,
                                        const float* __restrict__ bt,
                                        short* U, short* V, short* S1,
                                        int w, int l16, int q, int tid) {
  float bv0 = bias[32 * w + l16], bv1 = bias[32 * w + 16 + l16];
#pragma unroll
  for (int mt = 0; mt < 4; ++mt)
#pragma unroll
    for (int r = 0; r < 4; ++r) {
      int row = 16 * mt + 4 * q + r;
      acc[mt][0][r] += bv0 + b2f(buf[row * 136 + 32 * w + l16]);
      acc[mt][1][r] += bv1 + b2f(buf[row * 136 + 32 * w + 16 + l16]);
    }
#pragma unroll
  for (int mt = 0; mt < 4; ++mt)
#pragma unroll
    for (int r = 0; r < 4; ++r) {
      float v0 = acc[mt][0][r], v1 = acc[mt][1][r];
      float s = v0 + v1, sq = v0 * v0 + v1 * v1;
#pragma unroll
      for (int m = 1; m < 16; m <<= 1) { s += __shfl_xor(s, m); sq += __shfl_xor(sq, m); }
      if (l16 == 0) {
        int row = 16 * mt + 4 * q + r;
        float* pad = (float*)((w < 2 ? U : V) + row * 136 + 128);
        pad[(w & 1) * 2] = s;
        pad[(w & 1) * 2 + 1] = sq;
      }
    }
  __syncthreads();
  if (tid < 64) {
    const float* up = (const float*)(U + tid * 136 + 128);
    const float* vp = (const float*)(V + tid * 136 + 128);
    float s = up[0] + up[2] + vp[0] + vp[2];
    float sq = up[1] + up[3] + vp[1] + vp[3];
    float mu = s * (1.0f / 128.0f);
    float var = sq * (1.0f / 128.0f) - mu * mu;
    float* sp = (float*)(S1 + tid * 136 + 128);
    sp[0] = mu;
    sp[1] = rsqrtf(var + 1e-5f);
  }
  __syncthreads();
  float gg0 = g[32 * w + l16], bb0 = bt[32 * w + l16];
  float gg1 = g[32 * w + 16 + l16], bb1 = bt[32 * w + 16 + l16];
#pragma unroll
  for (int mt = 0; mt < 4; ++mt)
#pragma unroll
    for (int r = 0; r < 4; ++r) {
      int row = 16 * mt + 4 * q + r;
      const float* sp = (const float*)(S1 + row * 136 + 128);
      float mu = sp[0], rs = sp[1];
      buf[row * 136 + 32 * w + l16]      = f2b((acc[mt][0][r] - mu) * rs * gg0 + bb0);
      buf[row * 136 + 32 * w + 16 + l16] = f2b((acc[mt][1][r] - mu) * rs * gg1 + bb1);
    }
  __syncthreads();
}

// FFN: act = LN(act + W2 @ gelu(W1 @ act + b1) + b2), 128-col chunks via S1.
__device__ __forceinline__ void ffn4(short* act, short* S1, short* U, short* V,
                                     const short* __restrict__ w1, const float* __restrict__ b1,
                                     const short* __restrict__ w2, const float* __restrict__ b2,
                                     const float* __restrict__ g, const float* __restrict__ bt,
                                     int w, int l16, int q, int tid) {
  f32x4 acc2[4][2];
  zero_acc4(acc2);
#pragma unroll 1
  for (int c = 0; c < 4; ++c) {
    f32x4 h[4][2];
    zero_acc4(h);
    gemm4<2>(act, w1, 128, 128 * c + 32 * w, 0, l16, q, h);
    store_c4(h, b1 + 128 * c, S1, w, l16, q, true);
    __syncthreads();
    gemm4<2>(S1, w2, 512, 32 * w, 128 * c, l16, q, acc2);
    __syncthreads();
  }
  res_ln4(acc2, b2, act, g, bt, U, V, S1, w, l16, q, tid);
}

// ---------------------------------------------------------------------------
struct K1Args {
  const float* x;
  const short *wpep, *wtcr, *wvp, *wop, *wvt, *wot, *w1p, *w2p, *w1t, *w2t, *wh1;
  const float *bpep, *btcr, *bvp, *bop, *bvt, *bot;
  const float *g1p, *e1p, *g2p, *e2p, *g1t, *e1t, *g2t, *e2t;
  const float *b1p, *b2p, *b1t, *b2t, *bh1;
  float* stats;
  short* h1f;
};

__global__ __launch_bounds__(256, 3) void k1_body(K1Args A) {
  __shared__ __align__(16) short L[3 * 64 * 136];   // 52224 B -> 3 blocks/CU
  short* U = L;
  short* V = L + 64 * 136;
  short* S1 = L + 2 * 64 * 136;
  const int tid = threadIdx.x;
  const int w = tid >> 6, lane = tid & 63, l16 = lane & 15, q = lane >> 4;
  const size_t R0 = (size_t)blockIdx.x * 64;

  // ---- phase 1: x -> pep(U), tcr(V); A-frags direct from global fp32 ----
  f32x4 acc[4][2];
  float4 cb[2][4][2];
  const float* xbase = A.x + (R0 + l16) * 864 + 8 * q;
  auto ldx = [&](int bsel, int t) {
#pragma unroll
    for (int mt = 0; mt < 4; ++mt) {
      const float* p = xbase + mt * (16 * 864) + 32 * t;
      cb[bsel][mt][0] = *(const float4*)p;
      cb[bsel][mt][1] = *(const float4*)(p + 4);
    }
  };
  auto mkfrags = [&](int bsel, S8U* a) {
#pragma unroll
    for (int mt = 0; mt < 4; ++mt) {
      float vv[8] = {cb[bsel][mt][0].x, cb[bsel][mt][0].y, cb[bsel][mt][0].z, cb[bsel][mt][0].w,
                     cb[bsel][mt][1].x, cb[bsel][mt][1].y, cb[bsel][mt][1].z, cb[bsel][mt][1].w};
      a[mt].s = pack8(vv);
    }
  };

  ldx(0, 0); ldx(1, 1);
  zero_acc4(acc);
  const short* Wp1 = A.wpep + (size_t)(32 * w + l16) * 384 + 8 * q;
#pragma unroll 1
  for (int t = 0; t < 12; ++t) {
    S8U a[4];
    mkfrags(t & 1, a);
    ldx(t & 1, t + 2);                      // t+2 <= 13
#pragma unroll
    for (int n = 0; n < 2; ++n) {
      S8U b; b.s = *(const s16x8*)(Wp1 + (size_t)(16 * n) * 384 + 32 * t);
#pragma unroll
      for (int mt = 0; mt < 4; ++mt) acc[mt][n] = mfma_bf16(a[mt], b, acc[mt][n]);
    }
  }
  store_c4(acc, A.bpep, U, w, l16, q, false);
  zero_acc4(acc);
  const short* Wp2 = A.wtcr + (size_t)(32 * w + l16) * 480 + 8 * q;
#pragma unroll 1
  for (int t = 0; t < 15; ++t) {            // global x step 12+t; parity (12+t)&1 == t&1
    S8U a[4];
    mkfrags(t & 1, a);
    if (t < 13) ldx(t & 1, 14 + t);         // loads steps 14..26
#pragma unroll
    for (int n = 0; n < 2; ++n) {
      S8U b; b.s = *(const s16x8*)(Wp2 + (size_t)(16 * n) * 480 + 32 * t);
#pragma unroll
      for (int mt = 0; mt < 4; ++mt) acc[mt][n] = mfma_bf16(a[mt], b, acc[mt][n]);
    }
  }
  store_c4(acc, A.btcr, V, w, l16, q, false);
  __syncthreads();                          // U, V complete

  // ---- phase 2: attention-equivalent projections + LN ----
  f32x4 accT[4][2];
  zero_acc4(acc);
  gemm4<2>(U, A.wvt, 128, 32 * w, 0, l16, q, acc);     // H = pep @ wv_t2p^T
  store_c4(acc, A.bvt, S1, w, l16, q, false);
  zero_acc4(accT);
  gemm4<2>(V, A.wvp, 128, 32 * w, 0, l16, q, accT);    // T = tcr @ wv_p2t^T (held)
  __syncthreads();                          // S1(H) complete
  zero_acc4(acc);
  gemm4<2>(S1, A.wot, 128, 32 * w, 0, l16, q, acc);
  res_ln4(acc, A.bot, V, A.g1t, A.e1t, U, V, S1, w, l16, q, tid);   // V = ta
  store_c4(accT, A.bvp, S1, w, l16, q, false);
  __syncthreads();                          // S1(T) complete
  zero_acc4(acc);
  gemm4<2>(S1, A.wop, 128, 32 * w, 0, l16, q, acc);
  res_ln4(acc, A.bop, U, A.g1p, A.e1p, U, V, S1, w, l16, q, tid);   // U = pa

  // ---- phase 3: FFNs ----
  ffn4(U, S1, U, V, A.w1p, A.b1p, A.w2p, A.b2p, A.g2p, A.e2p, w, l16, q, tid);
  ffn4(V, S1, U, V, A.w1t, A.b1t, A.w2t, A.b2t, A.g2t, A.e2t, w, l16, q, tid);

  // ---- phase 4: h1 = [pa|ta] @ w_h1^T + b ; frag store + BN1 stats ----
  zero_acc4(acc);
  gemm4<2>(U, A.wh1, 256, 32 * w, 0, l16, q, acc);
  gemm4<2>(V, A.wh1, 256, 32 * w, 128, l16, q, acc);

  const int slice = (int)blockIdx.x & 15;
  union { s16x8 v8[4]; int i[16]; } ob;
#pragma unroll
  for (int n = 0; n < 2; ++n) {
    int col = 32 * w + 16 * n + l16;
    float bb = A.bh1[col];
    float ss = 0.f, qq = 0.f;
#pragma unroll
    for (int mt = 0; mt < 4; ++mt) {
      float v0 = acc[mt][n][0] + bb, v1 = acc[mt][n][1] + bb;
      float v2 = acc[mt][n][2] + bb, v3 = acc[mt][n][3] + bb;
      ss += (v0 + v1) + (v2 + v3);
      qq += (v0 * v0 + v1 * v1) + (v2 * v2 + v3 * v3);
      ob.i[mt * 4 + n * 2 + 0] = cvt2(v0, v1);        // shorts idx mt*8+n*4+{0,1}
      ob.i[mt * 4 + n * 2 + 1] = cvt2(v2, v3);        // shorts idx mt*8+n*4+{2,3}
    }
    ss += __shfl_xor(ss, 16); qq += __shfl_xor(qq, 16);
    ss += __shfl_xor(ss, 32); qq += __shfl_xor(qq, 32);
    if (q == 0) {
      atomicAdd(&A.stats[slice * 128 + col], ss);
      atomicAdd(&A.stats[2048 + slice * 128 + col], qq);
    }
  }
  short* hf = A.h1f + (size_t)blockIdx.x * 8192 + w * 2048 + lane * 32;
#pragma unroll
  for (int j = 0; j < 4; ++j) *(s16x8*)(hf + 8 * j) = ob.v8[j];
}

// ---------------------------------------------------------------------------
struct K2Args {
  const short* h1f;
  const short* wh2;
  const float *bh2, *bn1g, *bn1b;
  float* stats;
  short* h2f;
};

__global__ __launch_bounds__(256, 6) void k2_mid(K2Args A) {
  __shared__ __align__(16) short U[64 * 136];
  __shared__ float s1[128], t1[128];
  const int tid = threadIdx.x;
  const int w = tid >> 6, lane = tid & 63, l16 = lane & 15, q = lane >> 4;

  if (tid < 128) {
    float S = 0.f, Q = 0.f;
#pragma unroll
    for (int s = 0; s < 16; ++s) {
      S += A.stats[s * 128 + tid];
      Q += A.stats[2048 + s * 128 + tid];
    }
    float mu = S * (1.0f / 65536.0f);
    float var = Q * (1.0f / 65536.0f) - mu * mu;
    float sc = A.bn1g[tid] * rsqrtf(var + 1e-5f);
    s1[tid] = sc;
    t1[tid] = A.bn1b[tid] - mu * sc;
  }
  __syncthreads();

  const short* hf = A.h1f + (size_t)blockIdx.x * 8192 + w * 2048 + lane * 32;
  union { s16x8 v8[4]; short sh[32]; } ib;
#pragma unroll
  for (int j = 0; j < 4; ++j) ib.v8[j] = *(const s16x8*)(hf + 8 * j);
#pragma unroll
  for (int n = 0; n < 2; ++n) {
    int col = 32 * w + 16 * n + l16;
    float sc = s1[col], tc = t1[col];
#pragma unroll
    for (int mt = 0; mt < 4; ++mt)
#pragma unroll
      for (int r = 0; r < 4; ++r) {
        float f = gelu_f(b2f(ib.sh[mt * 8 + n * 4 + r]) * sc + tc);
        U[(16 * mt + 4 * q + r) * 136 + col] = f2b(f);
      }
  }
  __syncthreads();

  f32x4 acc[4][1];
  zero_acc4(acc);
  gemm4<1>(U, A.wh2, 128, 16 * w, 0, l16, q, acc);

  const int slice = (int)blockIdx.x & 15;
  int col = 16 * w + l16;
  float bb = A.bh2[col];
  float ss = 0.f, qq = 0.f;
  union { s16x8 v8[2]; int i[8]; } ob;
#pragma unroll
  for (int mt = 0; mt < 4; ++mt) {
    float v0 = acc[mt][0][0] + bb, v1 = acc[mt][0][1] + bb;
    float v2 = acc[mt][0][2] + bb, v3 = acc[mt][0][3] + bb;
    ss += (v0 + v1) + (v2 + v3);
    qq += (v0 * v0 + v1 * v1) + (v2 * v2 + v3 * v3);
    ob.i[mt * 2 + 0] = cvt2(v0, v1);
    ob.i[mt * 2 + 1] = cvt2(v2, v3);
  }
  ss += __shfl_xor(ss, 16); qq += __shfl_xor(qq, 16);
  ss += __shfl_xor(ss, 32); qq += __shfl_xor(qq, 32);
  if (q == 0) {
    atomicAdd(&A.stats[4096 + slice * 64 + col], ss);
    atomicAdd(&A.stats[5120 + slice * 64 + col], qq);
  }
  short* of = A.h2f + (size_t)blockIdx.x * 4096 + w * 1024 + lane * 16;
  *(s16x8*)of = ob.v8[0];
  *(s16x8*)(of + 8) = ob.v8[1];
}

// ---------------------------------------------------------------------------
struct K3Args {
  const short* h2f;
  const float *bn2g, *bn2b;
  const float* stats;
  const float *wout, *bout;
  float* out;
};

__global__ __launch_bounds__(256, 8) void k3_out(K3Args A) {
  __shared__ float s2[64], t2[64], wo[64];
  __shared__ float part[4][64];
  const int tid = threadIdx.x;
  const int w = tid >> 6, lane = tid & 63, l16 = lane & 15, q = lane >> 4;

  if (tid < 64) {
    float S = 0.f, Q = 0.f;
#pragma unroll
    for (int s = 0; s < 16; ++s) {
      S += A.stats[4096 + s * 64 + tid];
      Q += A.stats[5120 + s * 64 + tid];
    }
    float mu = S * (1.0f / 65536.0f);
    float var = Q * (1.0f / 65536.0f) - mu * mu;
    float sc = A.bn2g[tid] * rsqrtf(var + 1e-5f);
    s2[tid] = sc;
    t2[tid] = A.bn2b[tid] - mu * sc;
    wo[tid] = A.wout[tid];
  }
  __syncthreads();

  const short* hf = A.h2f + (size_t)blockIdx.x * 4096 + w * 1024 + lane * 16;
  union { s16x8 v8[2]; short sh[16]; } ib;
  ib.v8[0] = *(const s16x8*)hf;
  ib.v8[1] = *(const s16x8*)(hf + 8);
  int col = 16 * w + l16;
  float sc = s2[col], tc = t2[col], wc = wo[col];
  float rv[4][4];
#pragma unroll
  for (int mt = 0; mt < 4; ++mt)
#pragma unroll
    for (int r = 0; r < 4; ++r)
      rv[mt][r] = gelu_f(b2f(ib.sh[mt * 4 + r]) * sc + tc) * wc;
#pragma unroll
  for (int mt = 0; mt < 4; ++mt)
#pragma unroll
    for (int r = 0; r < 4; ++r) {
#pragma unroll
      for (int m = 1; m < 16; m <<= 1) rv[mt][r] += __shfl_xor(rv[mt][r], m);
    }
  if (l16 == 0) {
#pragma unroll
    for (int mt = 0; mt < 4; ++mt)
#pragma unroll
      for (int r = 0; r < 4; ++r) part[w][16 * mt + 4 * q + r] = rv[mt][r];
  }
  __syncthreads();
  if (tid < 64)
    A.out[(size_t)blockIdx.x * 64 + tid] =
        part[0][tid] + part[1][tid] + part[2][tid] + part[3][tid] + A.bout[0];
}

// ---------------------------------------------------------------------------
struct CvtArgs {
  const float* src[12];
  short* dst;
  float* stats;
};

__global__ __launch_bounds__(256) void k0_setup(CvtArgs A) {
  const int cum[13] = {0, 49152, 110592, 126976, 143360, 159744, 176128,
                       241664, 307200, 372736, 438272, 471040, 479232};
  int b = blockIdx.x;
  if (b < 24) A.stats[b * 256 + threadIdx.x] = 0.0f;
  int base = b * 1024;
  int seg = 0;
#pragma unroll
  for (int t = 1; t < 12; ++t) seg += (base >= cum[t]) ? 1 : 0;
  const float* s = A.src[seg];
  int loc = base - cum[seg] + threadIdx.x * 4;
  float4 f = *(const float4*)(s + loc);
  int di = base + threadIdx.x * 4;
  int2 p;
  p.x = cvt2(f.x, f.y);
  p.y = cvt2(f.z, f.w);
  *(int2*)(A.dst + di) = p;
}

// ---------------------------------------------------------------------------
extern "C" void kernel_launch(void* const* d_in, const int* in_sizes, int n_in,
                              void* d_out, int out_size, void* d_ws, size_t ws_size,
                              hipStream_t stream) {
  (void)in_sizes; (void)n_in; (void)out_size; (void)ws_size;
  char* ws = (char*)d_ws;
  short* wb = (short*)ws;
  enum { O_PEP = 0, O_TCR = 49152, O_VP2T = 110592, O_OP2T = 126976,
         O_VT2P = 143360, O_OT2P = 159744, O_W1P = 176128, O_W2P = 241664,
         O_W1T = 307200, O_W2T = 372736, O_H1 = 438272, O_H2 = 471040 };
  float* stats = (float*)(ws + 958464);     // 6144 floats (sliced BN stats)
  short* h1f   = (short*)(ws + 983040);     // 1024 blocks * 8192 shorts
  short* h2f   = (short*)(ws + 17760256);   // 1024 blocks * 4096 shorts

  CvtArgs ca;
  ca.src[0]  = (const float*)d_in[1];   // w_pep
  ca.src[1]  = (const float*)d_in[3];   // w_tcr
  ca.src[2]  = (const float*)d_in[5];   // wv_p2t
  ca.src[3]  = (const float*)d_in[7];   // wo_p2t
  ca.src[4]  = (const float*)d_in[9];   // wv_t2p
  ca.src[5]  = (const float*)d_in[11];  // wo_t2p
  ca.src[6]  = (const float*)d_in[21];  // ffn_w1p
  ca.src[7]  = (const float*)d_in[23];  // ffn_w2p
  ca.src[8]  = (const float*)d_in[25];  // ffn_w1t
  ca.src[9]  = (const float*)d_in[27];  // ffn_w2t
  ca.src[10] = (const float*)d_in[29];  // w_h1
  ca.src[11] = (const float*)d_in[33];  // w_h2
  ca.dst = wb;
  ca.stats = stats;
  k0_setup<<<468, 256, 0, stream>>>(ca);

  K1Args a;
  a.x = (const float*)d_in[0];
  a.wpep = wb + O_PEP; a.wtcr = wb + O_TCR;
  a.wvp = wb + O_VP2T; a.wop = wb + O_OP2T;
  a.wvt = wb + O_VT2P; a.wot = wb + O_OT2P;
  a.w1p = wb + O_W1P;  a.w2p = wb + O_W2P;
  a.w1t = wb + O_W1T;  a.w2t = wb + O_W2T;
  a.wh1 = wb + O_H1;
  a.bpep = (const float*)d_in[2];
  a.btcr = (const float*)d_in[4];
  a.bvp = (const float*)d_in[6];
  a.bop = (const float*)d_in[8];
  a.bvt = (const float*)d_in[10];
  a.bot = (const float*)d_in[12];
  a.g1p = (const float*)d_in[13]; a.e1p = (const float*)d_in[14];
  a.g2p = (const float*)d_in[15]; a.e2p = (const float*)d_in[16];
  a.g1t = (const float*)d_in[17]; a.e1t = (const float*)d_in[18];
  a.g2t = (const float*)d_in[19]; a.e2t = (const float*)d_in[20];
  a.b1p = (const float*)d_in[22];
  a.b2p = (const float*)d_in[24];
  a.b1t = (const float*)d_in[26];
  a.b2t = (const float*)d_in[28];
  a.bh1 = (const float*)d_in[30];
  a.stats = stats;
  a.h1f = h1f;
  k1_body<<<1024, 256, 0, stream>>>(a);

  K2Args b;
  b.h1f = h1f;
  b.wh2 = wb + O_H2;
  b.bh2 = (const float*)d_in[34];
  b.bn1g = (const float*)d_in[31];
  b.bn1b = (const float*)d_in[32];
  b.stats = stats;
  b.h2f = h2f;
  k2_mid<<<1024, 256, 0, stream>>>(b);

  K3Args c;
  c.h2f = h2f;
  c.bn2g = (const float*)d_in[35];
  c.bn2b = (const float*)d_in[36];
  c.stats = stats;
  c.wout = (const float*)d_in[37];
  c.bout = (const float*)d_in[38];
  c.out = (float*)d_out;
  k3_out<<<1024, 256, 0, stream>>>(c);
}

// Round 5
// 609.611 us; speedup vs baseline: 1.4231x; 1.3763x over previous
//
#include <hip/hip_runtime.h>
#include <hip/hip_bf16.h>
#include <math.h>

// ---------------------------------------------------------------------------
// CrossAttnMLP for gfx950 — cooperative 64-row blocks.
// R5: removed ALL dynamically-indexed private arrays (R3/R4 scratch-spill bug:
// cb[t&1] forced the prefetch buffers into scratch -> 858 MB writes). Phase 1
// now uses statically-named double buffers with manual unroll-by-2.
//  k0: weights fp32->bf16 + zero BN stat slices
//  k1: x -> transformer body -> h1 frags + BN1 sliced stats
//  k2: BN1+gelu -> h2 GEMM -> h2 frags + BN2 sliced stats
//  k3: BN2+gelu -> final dot
// ---------------------------------------------------------------------------

typedef __attribute__((ext_vector_type(8))) __bf16 bf16x8;
typedef __attribute__((ext_vector_type(2))) __bf16 bf16x2;
typedef __attribute__((ext_vector_type(8))) short s16x8;
typedef __attribute__((ext_vector_type(4))) float f32x4;

union S8U { s16x8 s; bf16x8 b; int i[4]; };

#if defined(__has_builtin)
#if __has_builtin(__builtin_amdgcn_cvt_pk_bf16_f32)
#define HAVE_PK_BF16 1
#endif
#endif

__device__ __forceinline__ short f2b(float f) {
  union { float f; unsigned u; } v; v.f = f;
  unsigned r = v.u + 0x7fffu + ((v.u >> 16) & 1u);   // RNE
  return (short)(r >> 16);
}
__device__ __forceinline__ float b2f(short s) {
  union { unsigned u; float f; } v; v.u = ((unsigned)(unsigned short)s) << 16;
  return v.f;
}
__device__ __forceinline__ int cvt2(float lo, float hi) {
#ifdef HAVE_PK_BF16
  union { bf16x2 v; int i; } u;
  u.v = __builtin_amdgcn_cvt_pk_bf16_f32(lo, hi);
  return u.i;
#else
  return ((int)(unsigned short)f2b(lo)) | (((int)(unsigned short)f2b(hi)) << 16);
#endif
}
// tanh-form gelu, branch-free
__device__ __forceinline__ float gelu_f(float x) {
  float u = x * (0.7978845608028654f + 0.035677408136300125f * x * x);
  float e = __expf(2.0f * u);
  float t = 1.0f - 2.0f / (e + 1.0f);
  return 0.5f * x * (1.0f + t);
}

__device__ __forceinline__ f32x4 mfma_bf16(const S8U& a, const S8U& b, f32x4 c) {
  return __builtin_amdgcn_mfma_f32_16x16x32_bf16(a.b, b.b, c, 0, 0, 0);
}

template<int NC>
__device__ __forceinline__ void zero_acc4(f32x4 (&acc)[4][NC]) {
  f32x4 z = {0.f, 0.f, 0.f, 0.f};
#pragma unroll
  for (int mt = 0; mt < 4; ++mt)
#pragma unroll
    for (int n = 0; n < NC; ++n) acc[mt][n] = z;
}

// acc[mt][n] += act(64x128 LDS, stride 136) @ W^T.
// W row-major (out,k) bf16; out col = wc0 + 16n + l16, k = kw0 + 32kt + 8q..
template<int NC>
__device__ __forceinline__ void gemm4(const short* act,
                                      const short* __restrict__ W, int ldw,
                                      int wc0, int kw0, int l16, int q,
                                      f32x4 (&acc)[4][NC]) {
  const short* Wp = W + (size_t)(wc0 + l16) * ldw + kw0 + 8 * q;
  const short* ap = act + l16 * 136 + 8 * q;
#pragma unroll
  for (int kt = 0; kt < 4; ++kt) {
    S8U a[4];
#pragma unroll
    for (int mt = 0; mt < 4; ++mt)
      a[mt].s = *(const s16x8*)(ap + mt * 16 * 136 + 32 * kt);
#pragma unroll
    for (int n = 0; n < NC; ++n) {
      S8U b; b.s = *(const s16x8*)(Wp + (size_t)(16 * n) * ldw + 32 * kt);
#pragma unroll
      for (int mt = 0; mt < 4; ++mt) acc[mt][n] = mfma_bf16(a[mt], b, acc[mt][n]);
    }
  }
}

// C-layout (row=16mt+4q+r, col=32w+16n+l16) -> row-major LDS, +bias, opt gelu.
__device__ __forceinline__ void store_c4(const f32x4 (&acc)[4][2], const float* __restrict__ bias,
                                         short* dst, int w, int l16, int q, bool do_gelu) {
#pragma unroll
  for (int n = 0; n < 2; ++n) {
    int col = 32 * w + 16 * n + l16;
    float bb = bias[col];
#pragma unroll
    for (int mt = 0; mt < 4; ++mt)
#pragma unroll
      for (int r = 0; r < 4; ++r) {
        float v = acc[mt][n][r] + bb;
        if (do_gelu) v = gelu_f(v);
        dst[(16 * mt + 4 * q + r) * 136 + col] = f2b(v);
      }
  }
}

// acc += bias + residual(buf); LayerNorm over 128 cols; write back to buf.
// Cross-wave row stats flow through the pad columns (col 128..135) of U/V
// (partials, 2 floats per wave) and S1 (mu/rsigma) — no dedicated LDS.
__device__ __forceinline__ void res_ln4(f32x4 (&acc)[4][2], const float* __restrict__ bias,
                                        short* buf, const float* __restrict__ g,
                                        const float* __restrict__ bt,
                                        short* U, short* V, short* S1,
                                        int w, int l16, int q, int tid) {
  float bv0 = bias[32 * w + l16], bv1 = bias[32 * w + 16 + l16];
#pragma unroll
  for (int mt = 0; mt < 4; ++mt)
#pragma unroll
    for (int r = 0; r < 4; ++r) {
      int row = 16 * mt + 4 * q + r;
      acc[mt][0][r] += bv0 + b2f(buf[row * 136 + 32 * w + l16]);
      acc[mt][1][r] += bv1 + b2f(buf[row * 136 + 32 * w + 16 + l16]);
    }
#pragma unroll
  for (int mt = 0; mt < 4; ++mt)
#pragma unroll
    for (int r = 0; r < 4; ++r) {
      float v0 = acc[mt][0][r], v1 = acc[mt][1][r];
      float s = v0 + v1, sq = v0 * v0 + v1 * v1;
#pragma unroll
      for (int m = 1; m < 16; m <<= 1) { s += __shfl_xor(s, m); sq += __shfl_xor(sq, m); }
      if (l16 == 0) {
        int row = 16 * mt + 4 * q + r;
        float* pad = (float*)((w < 2 ? U : V) + row * 136 + 128);
        pad[(w & 1) * 2] = s;
        pad[(w & 1) * 2 + 1] = sq;
      }
    }
  __syncthreads();
  if (tid < 64) {
    const float* up = (const float*)(U + tid * 136 + 128);
    const float* vp = (const float*)(V + tid * 136 + 128);
    float s = up[0] + up[2] + vp[0] + vp[2];
    float sq = up[1] + up[3] + vp[1] + vp[3];
    float mu = s * (1.0f / 128.0f);
    float var = sq * (1.0f / 128.0f) - mu * mu;
    float* sp = (float*)(S1 + tid * 136 + 128);
    sp[0] = mu;
    sp[1] = rsqrtf(var + 1e-5f);
  }
  __syncthreads();
  float gg0 = g[32 * w + l16], bb0 = bt[32 * w + l16];
  float gg1 = g[32 * w + 16 + l16], bb1 = bt[32 * w + 16 + l16];
#pragma unroll
  for (int mt = 0; mt < 4; ++mt)
#pragma unroll
    for (int r = 0; r < 4; ++r) {
      int row = 16 * mt + 4 * q + r;
      const float* sp = (const float*)(S1 + row * 136 + 128);
      float mu = sp[0], rs = sp[1];
      buf[row * 136 + 32 * w + l16]      = f2b((acc[mt][0][r] - mu) * rs * gg0 + bb0);
      buf[row * 136 + 32 * w + 16 + l16] = f2b((acc[mt][1][r] - mu) * rs * gg1 + bb1);
    }
  __syncthreads();
}

// FFN: act = LN(act + W2 @ gelu(W1 @ act + b1) + b2), 128-col chunks via S1.
__device__ __forceinline__ void ffn4(short* act, short* S1, short* U, short* V,
                                     const short* __restrict__ w1, const float* __restrict__ b1,
                                     const short* __restrict__ w2, const float* __restrict__ b2,
                                     const float* __restrict__ g, const float* __restrict__ bt,
                                     int w, int l16, int q, int tid) {
  f32x4 acc2[4][2];
  zero_acc4(acc2);
#pragma unroll 1
  for (int c = 0; c < 4; ++c) {
    f32x4 h[4][2];
    zero_acc4(h);
    gemm4<2>(act, w1, 128, 128 * c + 32 * w, 0, l16, q, h);
    store_c4(h, b1 + 128 * c, S1, w, l16, q, true);
    __syncthreads();
    gemm4<2>(S1, w2, 512, 32 * w, 128 * c, l16, q, acc2);
    __syncthreads();
  }
  res_ln4(acc2, b2, act, g, bt, U, V, S1, w, l16, q, tid);
}

// ---------------------------------------------------------------------------
struct K1Args {
  const float* x;
  const short *wpep, *wtcr, *wvp, *wop, *wvt, *wot, *w1p, *w2p, *w1t, *w2t, *wh1;
  const float *bpep, *btcr, *bvp, *bop, *bvt, *bot;
  const float *g1p, *e1p, *g2p, *e2p, *g1t, *e1t, *g2t, *e2t;
  const float *b1p, *b2p, *b1t, *b2t, *bh1;
  float* stats;
  short* h1f;
};

__global__ __launch_bounds__(256, 3) void k1_body(K1Args A) {
  __shared__ __align__(16) short L[3 * 64 * 136];   // 52224 B -> 3 blocks/CU
  short* U = L;
  short* V = L + 64 * 136;
  short* S1 = L + 2 * 64 * 136;
  const int tid = threadIdx.x;
  const int w = tid >> 6, lane = tid & 63, l16 = lane & 15, q = lane >> 4;
  const size_t R0 = (size_t)blockIdx.x * 64;

  // ---- phase 1: x -> pep(U), tcr(V); A-frags direct from global fp32 ----
  // Static double-buffers cA/cB, manual unroll-by-2: NO dynamic private
  // indexing anywhere (dynamic index => scratch allocation => HBM spill).
  f32x4 acc[4][2];
  float4 cA[4][2], cB[4][2];
  const float* xbase = A.x + (R0 + l16) * 864 + 8 * q;

  auto ldx = [&](float4 (&d)[4][2], int t) {
#pragma unroll
    for (int mt = 0; mt < 4; ++mt) {
      const float* p = xbase + mt * (16 * 864) + 32 * t;
      d[mt][0] = *(const float4*)p;
      d[mt][1] = *(const float4*)(p + 4);
    }
  };
  auto mk = [&](const float4 (&cc)[4][2], S8U (&a)[4]) {
#pragma unroll
    for (int mt = 0; mt < 4; ++mt) {
      union { s16x8 s; int i[4]; } u;
      u.i[0] = cvt2(cc[mt][0].x, cc[mt][0].y);
      u.i[1] = cvt2(cc[mt][0].z, cc[mt][0].w);
      u.i[2] = cvt2(cc[mt][1].x, cc[mt][1].y);
      u.i[3] = cvt2(cc[mt][1].z, cc[mt][1].w);
      a[mt].s = u.s;
    }
  };

  ldx(cA, 0); ldx(cB, 1);
  zero_acc4(acc);
  const short* Wp1 = A.wpep + (size_t)(32 * w + l16) * 384 + 8 * q;
#pragma unroll 1
  for (int t = 0; t < 12; t += 2) {
    S8U a[4];
    mk(cA, a);
    ldx(cA, t + 2);                           // steps 2,4,..,12
#pragma unroll
    for (int n = 0; n < 2; ++n) {
      S8U b; b.s = *(const s16x8*)(Wp1 + (size_t)(16 * n) * 384 + 32 * t);
#pragma unroll
      for (int mt = 0; mt < 4; ++mt) acc[mt][n] = mfma_bf16(a[mt], b, acc[mt][n]);
    }
    mk(cB, a);
    ldx(cB, t + 3);                           // steps 3,5,..,13
#pragma unroll
    for (int n = 0; n < 2; ++n) {
      S8U b; b.s = *(const s16x8*)(Wp1 + (size_t)(16 * n) * 384 + 32 * (t + 1));
#pragma unroll
      for (int mt = 0; mt < 4; ++mt) acc[mt][n] = mfma_bf16(a[mt], b, acc[mt][n]);
    }
  }
  store_c4(acc, A.bpep, U, w, l16, q, false);
  // exiting pep loop: cA = global step 12, cB = global step 13
  zero_acc4(acc);
  const short* Wp2 = A.wtcr + (size_t)(32 * w + l16) * 480 + 8 * q;
#pragma unroll 1
  for (int t = 0; t < 14; t += 2) {           // tcr local steps 0..13
    S8U a[4];
    mk(cA, a);
    ldx(cA, t + 14);                          // global steps 14,16,..,26
#pragma unroll
    for (int n = 0; n < 2; ++n) {
      S8U b; b.s = *(const s16x8*)(Wp2 + (size_t)(16 * n) * 480 + 32 * t);
#pragma unroll
      for (int mt = 0; mt < 4; ++mt) acc[mt][n] = mfma_bf16(a[mt], b, acc[mt][n]);
    }
    mk(cB, a);
    if (t < 12) ldx(cB, t + 15);              // global steps 15,..,25 (skip 27)
#pragma unroll
    for (int n = 0; n < 2; ++n) {
      S8U b; b.s = *(const s16x8*)(Wp2 + (size_t)(16 * n) * 480 + 32 * (t + 1));
#pragma unroll
      for (int mt = 0; mt < 4; ++mt) acc[mt][n] = mfma_bf16(a[mt], b, acc[mt][n]);
    }
  }
  {                                           // tail: local step 14 (global 26)
    S8U a[4];
    mk(cA, a);
#pragma unroll
    for (int n = 0; n < 2; ++n) {
      S8U b; b.s = *(const s16x8*)(Wp2 + (size_t)(16 * n) * 480 + 32 * 14);
#pragma unroll
      for (int mt = 0; mt < 4; ++mt) acc[mt][n] = mfma_bf16(a[mt], b, acc[mt][n]);
    }
  }
  store_c4(acc, A.btcr, V, w, l16, q, false);
  __syncthreads();                            // U, V complete

  // ---- phase 2: attention-equivalent projections + LN ----
  f32x4 accT[4][2];
  zero_acc4(acc);
  gemm4<2>(U, A.wvt, 128, 32 * w, 0, l16, q, acc);     // H = pep @ wv_t2p^T
  store_c4(acc, A.bvt, S1, w, l16, q, false);
  zero_acc4(accT);
  gemm4<2>(V, A.wvp, 128, 32 * w, 0, l16, q, accT);    // T = tcr @ wv_p2t^T (held)
  __syncthreads();                            // S1(H) complete
  zero_acc4(acc);
  gemm4<2>(S1, A.wot, 128, 32 * w, 0, l16, q, acc);
  res_ln4(acc, A.bot, V, A.g1t, A.e1t, U, V, S1, w, l16, q, tid);   // V = ta
  store_c4(accT, A.bvp, S1, w, l16, q, false);
  __syncthreads();                            // S1(T) complete
  zero_acc4(acc);
  gemm4<2>(S1, A.wop, 128, 32 * w, 0, l16, q, acc);
  res_ln4(acc, A.bop, U, A.g1p, A.e1p, U, V, S1, w, l16, q, tid);   // U = pa

  // ---- phase 3: FFNs ----
  ffn4(U, S1, U, V, A.w1p, A.b1p, A.w2p, A.b2p, A.g2p, A.e2p, w, l16, q, tid);
  ffn4(V, S1, U, V, A.w1t, A.b1t, A.w2t, A.b2t, A.g2t, A.e2t, w, l16, q, tid);

  // ---- phase 4: h1 = [pa|ta] @ w_h1^T + b ; frag store + BN1 stats ----
  zero_acc4(acc);
  gemm4<2>(U, A.wh1, 256, 32 * w, 0, l16, q, acc);
  gemm4<2>(V, A.wh1, 256, 32 * w, 128, l16, q, acc);

  const int slice = (int)blockIdx.x & 15;
  union { s16x8 v8[4]; int i[16]; } ob;
#pragma unroll
  for (int n = 0; n < 2; ++n) {
    int col = 32 * w + 16 * n + l16;
    float bb = A.bh1[col];
    float ss = 0.f, qq = 0.f;
#pragma unroll
    for (int mt = 0; mt < 4; ++mt) {
      float v0 = acc[mt][n][0] + bb, v1 = acc[mt][n][1] + bb;
      float v2 = acc[mt][n][2] + bb, v3 = acc[mt][n][3] + bb;
      ss += (v0 + v1) + (v2 + v3);
      qq += (v0 * v0 + v1 * v1) + (v2 * v2 + v3 * v3);
      ob.i[mt * 4 + n * 2 + 0] = cvt2(v0, v1);        // shorts idx mt*8+n*4+{0,1}
      ob.i[mt * 4 + n * 2 + 1] = cvt2(v2, v3);        // shorts idx mt*8+n*4+{2,3}
    }
    ss += __shfl_xor(ss, 16); qq += __shfl_xor(qq, 16);
    ss += __shfl_xor(ss, 32); qq += __shfl_xor(qq, 32);
    if (q == 0) {
      atomicAdd(&A.stats[slice * 128 + col], ss);
      atomicAdd(&A.stats[2048 + slice * 128 + col], qq);
    }
  }
  short* hf = A.h1f + (size_t)blockIdx.x * 8192 + w * 2048 + lane * 32;
#pragma unroll
  for (int j = 0; j < 4; ++j) *(s16x8*)(hf + 8 * j) = ob.v8[j];
}

// ---------------------------------------------------------------------------
struct K2Args {
  const short* h1f;
  const short* wh2;
  const float *bh2, *bn1g, *bn1b;
  float* stats;
  short* h2f;
};

__global__ __launch_bounds__(256, 4) void k2_mid(K2Args A) {
  __shared__ __align__(16) short U[64 * 136];
  __shared__ float s1[128], t1[128];
  const int tid = threadIdx.x;
  const int w = tid >> 6, lane = tid & 63, l16 = lane & 15, q = lane >> 4;

  if (tid < 128) {
    float S = 0.f, Q = 0.f;
#pragma unroll
    for (int s = 0; s < 16; ++s) {
      S += A.stats[s * 128 + tid];
      Q += A.stats[2048 + s * 128 + tid];
    }
    float mu = S * (1.0f / 65536.0f);
    float var = Q * (1.0f / 65536.0f) - mu * mu;
    float sc = A.bn1g[tid] * rsqrtf(var + 1e-5f);
    s1[tid] = sc;
    t1[tid] = A.bn1b[tid] - mu * sc;
  }
  __syncthreads();

  const short* hf = A.h1f + (size_t)blockIdx.x * 8192 + w * 2048 + lane * 32;
  union { s16x8 v8[4]; short sh[32]; } ib;
#pragma unroll
  for (int j = 0; j < 4; ++j) ib.v8[j] = *(const s16x8*)(hf + 8 * j);
#pragma unroll
  for (int n = 0; n < 2; ++n) {
    int col = 32 * w + 16 * n + l16;
    float sc = s1[col], tc = t1[col];
#pragma unroll
    for (int mt = 0; mt < 4; ++mt)
#pragma unroll
      for (int r = 0; r < 4; ++r) {
        float f = gelu_f(b2f(ib.sh[mt * 8 + n * 4 + r]) * sc + tc);
        U[(16 * mt + 4 * q + r) * 136 + col] = f2b(f);
      }
  }
  __syncthreads();

  f32x4 acc[4][1];
  zero_acc4(acc);
  gemm4<1>(U, A.wh2, 128, 16 * w, 0, l16, q, acc);

  const int slice = (int)blockIdx.x & 15;
  int col = 16 * w + l16;
  float bb = A.bh2[col];
  float ss = 0.f, qq = 0.f;
  union { s16x8 v8[2]; int i[8]; } ob;
#pragma unroll
  for (int mt = 0; mt < 4; ++mt) {
    float v0 = acc[mt][0][0] + bb, v1 = acc[mt][0][1] + bb;
    float v2 = acc[mt][0][2] + bb, v3 = acc[mt][0][3] + bb;
    ss += (v0 + v1) + (v2 + v3);
    qq += (v0 * v0 + v1 * v1) + (v2 * v2 + v3 * v3);
    ob.i[mt * 2 + 0] = cvt2(v0, v1);
    ob.i[mt * 2 + 1] = cvt2(v2, v3);
  }
  ss += __shfl_xor(ss, 16); qq += __shfl_xor(qq, 16);
  ss += __shfl_xor(ss, 32); qq += __shfl_xor(qq, 32);
  if (q == 0) {
    atomicAdd(&A.stats[4096 + slice * 64 + col], ss);
    atomicAdd(&A.stats[5120 + slice * 64 + col], qq);
  }
  short* of = A.h2f + (size_t)blockIdx.x * 4096 + w * 1024 + lane * 16;
  *(s16x8*)of = ob.v8[0];
  *(s16x8*)(of + 8) = ob.v8[1];
}

// ---------------------------------------------------------------------------
struct K3Args {
  const short* h2f;
  const float *bn2g, *bn2b;
  const float* stats;
  const float *wout, *bout;
  float* out;
};

__global__ __launch_bounds__(256, 4) void k3_out(K3Args A) {
  __shared__ float s2[64], t2[64], wo[64];
  __shared__ float part[4][64];
  const int tid = threadIdx.x;
  const int w = tid >> 6, lane = tid & 63, l16 = lane & 15, q = lane >> 4;

  if (tid < 64) {
    float S = 0.f, Q = 0.f;
#pragma unroll
    for (int s = 0; s < 16; ++s) {
      S += A.stats[4096 + s * 64 + tid];
      Q += A.stats[5120 + s * 64 + tid];
    }
    float mu = S * (1.0f / 65536.0f);
    float var = Q * (1.0f / 65536.0f) - mu * mu;
    float sc = A.bn2g[tid] * rsqrtf(var + 1e-5f);
    s2[tid] = sc;
    t2[tid] = A.bn2b[tid] - mu * sc;
    wo[tid] = A.wout[tid];
  }
  __syncthreads();

  const short* hf = A.h2f + (size_t)blockIdx.x * 4096 + w * 1024 + lane * 16;
  union { s16x8 v8[2]; short sh[16]; } ib;
  ib.v8[0] = *(const s16x8*)hf;
  ib.v8[1] = *(const s16x8*)(hf + 8);
  int col = 16 * w + l16;
  float sc = s2[col], tc = t2[col], wc = wo[col];
  float rv[4][4];
#pragma unroll
  for (int mt = 0; mt < 4; ++mt)
#pragma unroll
    for (int r = 0; r < 4; ++r)
      rv[mt][r] = gelu_f(b2f(ib.sh[mt * 4 + r]) * sc + tc) * wc;
#pragma unroll
  for (int mt = 0; mt < 4; ++mt)
#pragma unroll
    for (int r = 0; r < 4; ++r) {
#pragma unroll
      for (int m = 1; m < 16; m <<= 1) rv[mt][r] += __shfl_xor(rv[mt][r], m);
    }
  if (l16 == 0) {
#pragma unroll
    for (int mt = 0; mt < 4; ++mt)
#pragma unroll
      for (int r = 0; r < 4; ++r) part[w][16 * mt + 4 * q + r] = rv[mt][r];
  }
  __syncthreads();
  if (tid < 64)
    A.out[(size_t)blockIdx.x * 64 + tid] =
        part[0][tid] + part[1][tid] + part[2][tid] + part[3][tid] + A.bout[0];
}

// ---------------------------------------------------------------------------
struct CvtArgs {
  const float* src[12];
  short* dst;
  float* stats;
};

__global__ __launch_bounds__(256) void k0_setup(CvtArgs A) {
  const int cum[13] = {0, 49152, 110592, 126976, 143360, 159744, 176128,
                       241664, 307200, 372736, 438272, 471040, 479232};
  int b = blockIdx.x;
  if (b < 24) A.stats[b * 256 + threadIdx.x] = 0.0f;
  int base = b * 1024;
  int seg = 0;
#pragma unroll
  for (int t = 1; t < 12; ++t) seg += (base >= cum[t]) ? 1 : 0;
  const float* s = A.src[seg];
  int loc = base - cum[seg] + threadIdx.x * 4;
  float4 f = *(const float4*)(s + loc);
  int di = base + threadIdx.x * 4;
  int2 p;
  p.x = cvt2(f.x, f.y);
  p.y = cvt2(f.z, f.w);
  *(int2*)(A.dst + di) = p;
}

// ---------------------------------------------------------------------------
extern "C" void kernel_launch(void* const* d_in, const int* in_sizes, int n_in,
                              void* d_out, int out_size, void* d_ws, size_t ws_size,
                              hipStream_t stream) {
  (void)in_sizes; (void)n_in; (void)out_size; (void)ws_size;
  char* ws = (char*)d_ws;
  short* wb = (short*)ws;
  enum { O_PEP = 0, O_TCR = 49152, O_VP2T = 110592, O_OP2T = 126976,
         O_VT2P = 143360, O_OT2P = 159744, O_W1P = 176128, O_W2P = 241664,
         O_W1T = 307200, O_W2T = 372736, O_H1 = 438272, O_H2 = 471040 };
  float* stats = (float*)(ws + 958464);     // 6144 floats (sliced BN stats)
  short* h1f   = (short*)(ws + 983040);     // 1024 blocks * 8192 shorts
  short* h2f   = (short*)(ws + 17760256);   // 1024 blocks * 4096 shorts

  CvtArgs ca;
  ca.src[0]  = (const float*)d_in[1];   // w_pep
  ca.src[1]  = (const float*)d_in[3];   // w_tcr
  ca.src[2]  = (const float*)d_in[5];   // wv_p2t
  ca.src[3]  = (const float*)d_in[7];   // wo_p2t
  ca.src[4]  = (const float*)d_in[9];   // wv_t2p
  ca.src[5]  = (const float*)d_in[11];  // wo_t2p
  ca.src[6]  = (const float*)d_in[21];  // ffn_w1p
  ca.src[7]  = (const float*)d_in[23];  // ffn_w2p
  ca.src[8]  = (const float*)d_in[25];  // ffn_w1t
  ca.src[9]  = (const float*)d_in[27];  // ffn_w2t
  ca.src[10] = (const float*)d_in[29];  // w_h1
  ca.src[11] = (const float*)d_in[33];  // w_h2
  ca.dst = wb;
  ca.stats = stats;
  k0_setup<<<468, 256, 0, stream>>>(ca);

  K1Args a;
  a.x = (const float*)d_in[0];
  a.wpep = wb + O_PEP; a.wtcr = wb + O_TCR;
  a.wvp = wb + O_VP2T; a.wop = wb + O_OP2T;
  a.wvt = wb + O_VT2P; a.wot = wb + O_OT2P;
  a.w1p = wb + O_W1P;  a.w2p = wb + O_W2P;
  a.w1t = wb + O_W1T;  a.w2t = wb + O_W2T;
  a.wh1 = wb + O_H1;
  a.bpep = (const float*)d_in[2];
  a.btcr = (const float*)d_in[4];
  a.bvp = (const float*)d_in[6];
  a.bop = (const float*)d_in[8];
  a.bvt = (const float*)d_in[10];
  a.bot = (const float*)d_in[12];
  a.g1p = (const float*)d_in[13]; a.e1p = (const float*)d_in[14];
  a.g2p = (const float*)d_in[15]; a.e2p = (const float*)d_in[16];
  a.g1t = (const float*)d_in[17]; a.e1t = (const float*)d_in[18];
  a.g2t = (const float*)d_in[19]; a.e2t = (const float*)d_in[20];
  a.b1p = (const float*)d_in[22];
  a.b2p = (const float*)d_in[24];
  a.b1t = (const float*)d_in[26];
  a.b2t = (const float*)d_in[28];
  a.bh1 = (const float*)d_in[30];
  a.stats = stats;
  a.h1f = h1f;
  k1_body<<<1024, 256, 0, stream>>>(a);

  K2Args b;
  b.h1f = h1f;
  b.wh2 = wb + O_H2;
  b.bh2 = (const float*)d_in[34];
  b.bn1g = (const float*)d_in[31];
  b.bn1b = (const float*)d_in[32];
  b.stats = stats;
  b.h2f = h2f;
  k2_mid<<<1024, 256, 0, stream>>>(b);

  K3Args c;
  c.h2f = h2f;
  c.bn2g = (const float*)d_in[35];
  c.bn2b = (const float*)d_in[36];
  c.stats = stats;
  c.wout = (const float*)d_in[37];
  c.bout = (const float*)d_in[38];
  c.out = (float*)d_out;
  k3_out<<<1024, 256, 0, stream>>>(c);
}